// Round 9
// baseline (410.582 us; speedup 1.0000x reference)
//
#include <hip/hip_runtime.h>
#include <hip/hip_bf16.h>
#include <math.h>

// Problem constants
#define Bc 2
#define Tc 2048
#define Cc 1024
#define Hc 16
#define Dc 64
// SCALE = 1/8, GAMMA = 8

typedef __attribute__((ext_vector_type(8))) short short8;   // 8 bf16 (4 VGPRs)
typedef __attribute__((ext_vector_type(4))) float f32x4;    // MFMA C/D frag

#define L2E 1.44269504088896f
#define SM_M 20.0f   // fixed softmax shift; |scores| << 20 (std ~0.3)

__device__ __forceinline__ short f2bf(float x) {
    unsigned u = __float_as_uint(x);
    u += 0x7fff + ((u >> 16) & 1);      // RNE
    return (short)(u >> 16);
}
// pack two non-negative floats to bf16 pair (round-half-up) in 3 VALU ops
__device__ __forceinline__ unsigned pack2bf_fast(float a, float b) {
    unsigned ua = __float_as_uint(a) + 0x8000u;
    unsigned ub = __float_as_uint(b) + 0x8000u;
    return __builtin_amdgcn_perm(ub, ua, 0x07060302);  // (ua>>16)|(ub&0xffff0000)
}
// fast softplus: 2 HW transcendentals, ~1e-6 rel err (invisible at bf16)
__device__ __forceinline__ float softplus_fast(float a) {
    return fmaxf(a, 0.f) + __logf(1.f + __expf(-fabsf(a)));
}

// ---------------------------------------------------------------------------
// 256x256 8-phase bf16 GEMM with fused moire-QK epilogue (m201 template).
// R6: + XCD-aware bijective block swizzle (T1).  (unchanged from R8-verified)
// ---------------------------------------------------------------------------
#define RDA(BUF, MH) do {                                                      \
    const short* Ah_ = &Al[BUF][MH][0];                                        \
    _Pragma("unroll") for (int mt_ = 0; mt_ < 4; ++mt_) {                      \
        af[mt_][0] = *(const short8*)&Ah_[(wm*64 + mt_*16 + c)*64 + rsw0];     \
        af[mt_][1] = *(const short8*)&Ah_[(wm*64 + mt_*16 + c)*64 + rsw1];     \
    } } while (0)

#define RDB(BUF, NH) do {                                                      \
    const short* Bh_ = &Bl[BUF][NH][0];                                        \
    _Pragma("unroll") for (int nf_ = 0; nf_ < 2; ++nf_) {                      \
        bfr[NH][nf_][0] = *(const short8*)&Bh_[(wn*32 + nf_*16 + c)*64 + rsw0];\
        bfr[NH][nf_][1] = *(const short8*)&Bh_[(wn*32 + nf_*16 + c)*64 + rsw1];\
    } } while (0)

#define MMQ(MH, NH) do {                                                       \
    _Pragma("unroll") for (int mt_ = 0; mt_ < 4; ++mt_)                        \
    _Pragma("unroll") for (int nf_ = 0; nf_ < 2; ++nf_) {                      \
        acc[MH][NH][mt_][nf_] = __builtin_amdgcn_mfma_f32_16x16x32_bf16(       \
            af[mt_][0], bfr[NH][nf_][0], acc[MH][NH][mt_][nf_], 0, 0, 0);      \
        acc[MH][NH][mt_][nf_] = __builtin_amdgcn_mfma_f32_16x16x32_bf16(       \
            af[mt_][1], bfr[NH][nf_][1], acc[MH][NH][mt_][nf_], 0, 0, 0);      \
    } } while (0)

#define BARw asm volatile("s_barrier" ::: "memory")
#define VMW6 asm volatile("s_waitcnt vmcnt(6)" ::: "memory")
#define VMW0 asm volatile("s_waitcnt vmcnt(0)" ::: "memory")
#define PRIO1 __builtin_amdgcn_s_setprio(1)
#define PRIO0 __builtin_amdgcn_s_setprio(0)

__global__ __launch_bounds__(512, 2) void gemm256_qk(
    const short* __restrict__ A, const short* __restrict__ Bt,
    short* __restrict__ q2, short* __restrict__ k2)
{
    __shared__ __attribute__((aligned(16))) short Al[2][2][128 * 64];  // 64 KB
    __shared__ __attribute__((aligned(16))) short Bl[2][2][128 * 64];  // 64 KB

    const int tid = threadIdx.x;
    const int wave = tid >> 6, lane = tid & 63;
    const int quad = lane >> 4, c = lane & 15;
    const int wm = wave >> 2, wn = wave & 3;          // 2M x 4N waves
    // XCD-chunked bijective swizzle: f%8 = XCD (round-robin dispatch);
    // XCD k owns w in [32k,32k+32) = 2 full grid rows -> A-panel L2 reuse.
    const int f = blockIdx.x + 16 * blockIdx.y;       // 0..255
    const int w = (f & 7) * 32 + (f >> 3);
    const int bx = w & 15, by = w >> 4;
    const int m0 = by * 256, n0 = bx * 256;

    // swizzled ds_read byte-slot (shorts): (ks*64 + quad*16) ^ ((c&7)<<4)
    const int rsw0 = ((quad * 16) ^ ((c & 7) << 4)) >> 1;
    const int rsw1 = ((64 + quad * 16) ^ ((c & 7) << 4)) >> 1;

    f32x4 acc[2][2][4][2];
#pragma unroll
    for (int a0 = 0; a0 < 2; ++a0)
#pragma unroll
        for (int a1 = 0; a1 < 2; ++a1)
#pragma unroll
            for (int a2 = 0; a2 < 4; ++a2)
#pragma unroll
                for (int a3 = 0; a3 < 2; ++a3)
                    acc[a0][a1][a2][a3] = (f32x4){0.f, 0.f, 0.f, 0.f};

    short8 af[4][2];        // A-frags: 4 m-frags x 2 k-steps (32 VGPR)
    short8 bfr[2][2][2];    // B-frags: [nh][nf][ks] both halves kept (32 VGPR)

    auto stA = [&](int kt, int hh) {
        short* dstb = &Al[kt & 1][hh][0];
#pragma unroll
        for (int j = 0; j < 2; ++j) {
            int ch = j * 512 + tid;
            int row = ch >> 3;
            int os = ((((ch & 7) << 4) ^ ((row & 7) << 4)) >> 1);
            const short* src = A + (size_t)(m0 + hh * 128 + row) * 1024 + kt * 64 + os;
            __builtin_amdgcn_global_load_lds(
                (const __attribute__((address_space(1))) void*)src,
                (__attribute__((address_space(3))) void*)(dstb + (j * 512 + wave * 64) * 8),
                16, 0, 0);
        }
    };
    auto stB = [&](int kt, int hh) {
        short* dstb = &Bl[kt & 1][hh][0];
#pragma unroll
        for (int j = 0; j < 2; ++j) {
            int ch = j * 512 + tid;
            int row = ch >> 3;
            int os = ((((ch & 7) << 4) ^ ((row & 7) << 4)) >> 1);
            const short* src = Bt + (size_t)(n0 + hh * 128 + row) * 1024 + kt * 64 + os;
            __builtin_amdgcn_global_load_lds(
                (const __attribute__((address_space(1))) void*)src,
                (__attribute__((address_space(3))) void*)(dstb + (j * 512 + wave * 64) * 8),
                16, 0, 0);
        }
    };

    // prologue: tile0 fully + tile1 {Bh0, Ah0, Bh1}; Ah1(1) comes at p1 of i=0.
    stB(0, 0); stA(0, 0); stB(0, 1); stA(0, 1); stB(1, 0); stA(1, 0); stB(1, 1);
    VMW6;          // oldest 8 loads (= all of tile 0) landed
    BARw;

    // K = 1024 -> 16 K-tiles -> 8 iterations of 2 tiles (buf0 = even tile).
    for (int i = 0; i < 8; ++i) {
        const int e = 2 * i;
        const bool more = (i < 7);
        // ---- group e (buf 0) ----
        RDA(0, 0); RDB(0, 0);                 // p1: 12 ds_reads
        stA(e + 1, 1);                        //     stage Ah1(odd tile)
        BARw; PRIO1; MMQ(0, 0); PRIO0; BARw;
        RDB(0, 1);                            // p2: 4 ds_reads (A kept)
        if (more) stB(e + 2, 0);
        BARw; PRIO1; MMQ(0, 1); PRIO0; BARw;
        RDA(0, 1);                            // p3: 8 ds_reads (B0 kept)
        if (more) stA(e + 2, 0);
        BARw; PRIO1; MMQ(1, 0); PRIO0; BARw;
        if (more) stB(e + 2, 1);              // p4: no ds_reads (A,B1 kept)
        BARw; PRIO1; MMQ(1, 1); PRIO0;
        if (more) { VMW6; } else { VMW0; }
        BARw;
        // ---- group o (buf 1) ----
        RDA(1, 0); RDB(1, 0);                 // p5
        if (more) stA(e + 2, 1);
        BARw; PRIO1; MMQ(0, 0); PRIO0; BARw;
        RDB(1, 1);                            // p6
        if (more) stB(e + 3, 0);
        BARw; PRIO1; MMQ(0, 1); PRIO0; BARw;
        RDA(1, 1);                            // p7
        if (more) stA(e + 3, 0);
        BARw; PRIO1; MMQ(1, 0); PRIO0; BARw;
        if (more) stB(e + 3, 1);              // p8
        BARw; PRIO1; MMQ(1, 1); PRIO0;
        if (more) { VMW6; } else { VMW0; }
        BARw;
    }

    // moire epilogue: cols of this lane: n = n0 + nh*128 + wn*32 + nf*16 + c
    const int d = wn * 16 + c;
#pragma unroll
    for (int mh = 0; mh < 2; ++mh) {
#pragma unroll
        for (int nh = 0; nh < 2; ++nh) {
            const int g = 2 * bx + nh;
            const int isK = g >> 4;
            const int hh = g & 15;
            const float scl = isK ? 1.f : 0.125f;
            short* dst = isK ? k2 : q2;       // (B,H,T,128)
#pragma unroll
            for (int mt = 0; mt < 4; ++mt) {
#pragma unroll
                for (int reg = 0; reg < 4; ++reg) {
                    int m = m0 + mh * 128 + wm * 64 + mt * 16 + quad * 4 + reg;
                    int bb = m >> 11, tt = m & (Tc - 1);
                    size_t base = (((size_t)bb * Hc + hh) * Tc + tt) * 128;
                    float amp = acc[mh][nh][mt][0][reg];
                    float ph  = acc[mh][nh][mt][1][reg];
                    float sp = softplus_fast(amp) * scl;
                    float sn, cs;
                    __sincosf(ph, &sn, &cs);
                    dst[base + d]      = f2bf(sp * cs);
                    dst[base + d + 64] = f2bf(sp * sn);
                }
            }
        }
    }
}

// ---------------------------------------------------------------------------
// bf16 MFMA GEMM, 512-thread variant (R5). 4M x 2N waves, 32x64 per wave.
// ---------------------------------------------------------------------------
template <int EPI>
__global__ __launch_bounds__(512) void gemm_bt_mfma(
    const short* __restrict__ A, const short* __restrict__ Bt,
    float* __restrict__ Cf, short* __restrict__ Cb,
    int M, int N, int K)
{
    __shared__ __attribute__((aligned(16))) short As[128 * 32];
    __shared__ __attribute__((aligned(16))) short Bs[128 * 32];

    const int tid = threadIdx.x;
    const int lane = tid & 63;
    const int wave = tid >> 6;
    const int quad = lane >> 4, c = lane & 15;
    const int wm = wave >> 1, wn = wave & 1;          // 4M x 2N waves
    const int m0 = blockIdx.y * 128, n0 = blockIdx.x * 128;

    const int srow = tid >> 2;                        // 0..127
    const int scol = (tid & 3) * 8;
    const short* Ag = A  + (size_t)(m0 + srow) * K + scol;
    const short* Bg = Bt + (size_t)(n0 + srow) * K + scol;
    short* AsW = As + tid * 8;
    short* BsW = Bs + tid * 8;

    f32x4 acc[2][4];
#pragma unroll
    for (int i = 0; i < 2; ++i)
#pragma unroll
        for (int j = 0; j < 4; ++j)
            acc[i][j] = (f32x4){0.f, 0.f, 0.f, 0.f};

    for (int k0 = 0; k0 < K; k0 += 32) {
        __syncthreads();
        __builtin_amdgcn_global_load_lds(
            (const __attribute__((address_space(1))) void*)(Ag + k0),
            (__attribute__((address_space(3))) void*)AsW, 16, 0, 0);
        __builtin_amdgcn_global_load_lds(
            (const __attribute__((address_space(1))) void*)(Bg + k0),
            (__attribute__((address_space(3))) void*)BsW, 16, 0, 0);
        __syncthreads();

        short8 af[2], bf[4];
#pragma unroll
        for (int mt = 0; mt < 2; ++mt)
            af[mt] = *(const short8*)&As[(wm * 32 + mt * 16 + c) * 32 + quad * 8];
#pragma unroll
        for (int nt = 0; nt < 4; ++nt)
            bf[nt] = *(const short8*)&Bs[(wn * 64 + nt * 16 + c) * 32 + quad * 8];
#pragma unroll
        for (int mt = 0; mt < 2; ++mt)
#pragma unroll
            for (int nt = 0; nt < 4; ++nt)
                acc[mt][nt] = __builtin_amdgcn_mfma_f32_16x16x32_bf16(
                    af[mt], bf[nt], acc[mt][nt], 0, 0, 0);
    }

#pragma unroll
    for (int mt = 0; mt < 2; ++mt) {
#pragma unroll
        for (int reg = 0; reg < 4; ++reg) {
            size_t row = m0 + wm * 32 + mt * 16 + quad * 4 + reg;
#pragma unroll
            for (int nt = 0; nt < 4; ++nt) {
                size_t col = n0 + wn * 64 + nt * 16 + c;
                if (EPI == 1) Cb[row * N + col] = f2bf(acc[mt][nt][reg]);
                else          Cf[row * N + col] = acc[mt][nt][reg];
            }
        }
    }
}

// ---------------------------------------------------------------------------
// V projection fused with head-transpose: v2t[(b,h,d),t] = (xb @ Wvt^T).
// 512-thread variant (R5).
// ---------------------------------------------------------------------------
__global__ __launch_bounds__(512) void gemm_v2t(
    const short* __restrict__ A, const short* __restrict__ Bt,
    short* __restrict__ v2t)
{
    __shared__ __attribute__((aligned(16))) short As[128 * 32];
    __shared__ __attribute__((aligned(16))) short Bs[128 * 32];
    __shared__ __attribute__((aligned(16))) short tile[128 * 136];  // [n][t]

    const int K = Cc;
    const int tid = threadIdx.x;
    const int lane = tid & 63;
    const int wave = tid >> 6;
    const int quad = lane >> 4, c = lane & 15;
    const int wm = wave >> 1, wn = wave & 1;          // 4M x 2N waves
    const int m0 = blockIdx.y * 128, n0 = blockIdx.x * 128;

    const int srow = tid >> 2;
    const int scol = (tid & 3) * 8;
    const short* Ag = A  + (size_t)(m0 + srow) * K + scol;
    const short* Bg = Bt + (size_t)(n0 + srow) * K + scol;
    short* AsW = As + tid * 8;
    short* BsW = Bs + tid * 8;

    f32x4 acc[2][4];
#pragma unroll
    for (int i = 0; i < 2; ++i)
#pragma unroll
        for (int j = 0; j < 4; ++j)
            acc[i][j] = (f32x4){0.f, 0.f, 0.f, 0.f};

    for (int k0 = 0; k0 < K; k0 += 32) {
        __syncthreads();
        __builtin_amdgcn_global_load_lds(
            (const __attribute__((address_space(1))) void*)(Ag + k0),
            (__attribute__((address_space(3))) void*)AsW, 16, 0, 0);
        __builtin_amdgcn_global_load_lds(
            (const __attribute__((address_space(1))) void*)(Bg + k0),
            (__attribute__((address_space(3))) void*)BsW, 16, 0, 0);
        __syncthreads();

        short8 af[2], bf[4];
#pragma unroll
        for (int mt = 0; mt < 2; ++mt)
            af[mt] = *(const short8*)&As[(wm * 32 + mt * 16 + c) * 32 + quad * 8];
#pragma unroll
        for (int nt = 0; nt < 4; ++nt)
            bf[nt] = *(const short8*)&Bs[(wn * 64 + nt * 16 + c) * 32 + quad * 8];
#pragma unroll
        for (int mt = 0; mt < 2; ++mt)
#pragma unroll
            for (int nt = 0; nt < 4; ++nt)
                acc[mt][nt] = __builtin_amdgcn_mfma_f32_16x16x32_bf16(
                    af[mt], bf[nt], acc[mt][nt], 0, 0, 0);
    }

    // epilogue: stash transposed into LDS [n][t]
#pragma unroll
    for (int mt = 0; mt < 2; ++mt)
#pragma unroll
        for (int reg = 0; reg < 4; ++reg) {
            int tl = wm * 32 + mt * 16 + quad * 4 + reg;
#pragma unroll
            for (int nt = 0; nt < 4; ++nt)
                tile[(wn * 64 + nt * 16 + c) * 136 + tl] = f2bf(acc[mt][nt][reg]);
        }
    __syncthreads();

    const int b = m0 >> 11, tl0 = m0 & (Tc - 1);
#pragma unroll
    for (int i = 0; i < 4; ++i) {
        int n = i * 32 + (tid >> 4);
        int t8 = (tid & 15) * 8;
        int ng = n0 + n, h = ng >> 6, d = ng & 63;
        *(short8*)&v2t[(((size_t)b * Hc + h) * Dc + d) * Tc + tl0 + t8] =
            *(const short8*)&tile[n * 136 + t8];
    }
}

// ---------------------------------------------------------------------------
__global__ __launch_bounds__(256) void xconv(const float* __restrict__ x,
                                             short* __restrict__ xb)
{
    int idx = blockIdx.x * 256 + threadIdx.x;
    float4 v = *(const float4*)&x[(size_t)idx * 4];
    short4 o = {f2bf(v.x), f2bf(v.y), f2bf(v.z), f2bf(v.w)};
    *(short4*)&xb[(size_t)idx * 4] = o;
}

// ---------------------------------------------------------------------------
// Wq|Wk transpose-convert with the gemm256_qk row permutation.
// ---------------------------------------------------------------------------
__global__ __launch_bounds__(256) void wtrans_qk(const float* __restrict__ Wq,
                                                 const float* __restrict__ Wk,
                                                 short* __restrict__ Bt)
{
    __shared__ short tile[64][80];
    const int n0 = blockIdx.x * 64, k0 = blockIdx.y * 64;
    const int half = blockIdx.z;
    const float* W = half ? Wk : Wq;
    const int tid = threadIdx.x;
#pragma unroll
    for (int i = 0; i < 4; ++i) {
        int e = i * 256 + tid;
        int k = e >> 4, n4 = (e & 15) * 4;
        float4 v = *(const float4*)&W[(size_t)(k0 + k) * 2048 + n0 + n4];
        tile[k][n4]     = f2bf(v.x);
        tile[k][n4 + 1] = f2bf(v.y);
        tile[k][n4 + 2] = f2bf(v.z);
        tile[k][n4 + 3] = f2bf(v.w);
    }
    __syncthreads();
#pragma unroll
    for (int i = 0; i < 16; ++i) {
        int e = i * 256 + tid;
        int n = e >> 6, k = e & 63;
        int ng = n0 + n;
        int sub = ng >> 10, hh = (ng >> 6) & 15, dd = ng & 63;
        int r = (half * 16 + hh) * 128 + (dd >> 4) * 32 + sub * 16 + (dd & 15);
        Bt[(size_t)r * Cc + k0 + k] = tile[k][n];
    }
}

// ---------------------------------------------------------------------------
__global__ __launch_bounds__(256) void wtrans2(const float* __restrict__ Wv,
                                               const float* __restrict__ Wo,
                                               short* __restrict__ WtBase)
{
    __shared__ short tile[64][80];
    const int n0 = blockIdx.x * 64, k0 = blockIdx.y * 64;
    const float* W = blockIdx.z ? Wo : Wv;
    short* Wt = WtBase + (size_t)blockIdx.z * Cc * Cc;
    const int tid = threadIdx.x;
#pragma unroll
    for (int i = 0; i < 4; ++i) {
        int e = i * 256 + tid;
        int k = e >> 4, n4 = (e & 15) * 4;
        float4 v = *(const float4*)&W[(size_t)(k0 + k) * Cc + n0 + n4];
        tile[k][n4]     = f2bf(v.x);
        tile[k][n4 + 1] = f2bf(v.y);
        tile[k][n4 + 2] = f2bf(v.z);
        tile[k][n4 + 3] = f2bf(v.w);
    }
    __syncthreads();
#pragma unroll
    for (int i = 0; i < 16; ++i) {
        int e = i * 256 + tid;
        int n = e >> 6, k = e & 63;
        Wt[(size_t)(n0 + n) * Cc + k0 + k] = tile[k][n];
    }
}

// ---------------------------------------------------------------------------
// MFMA flash attention v9 = v8 + XCD swizzle (R8-verified: FETCH 124->22MB)
// + T14 async-STAGE for phase 2 (R9): phase-2 staging becomes reg-staged
// prefetch -- issue 6 global loads (4 K-chunks + 2 V-chunks, 24 VGPR) for
// tile jt+1 BEFORE computing tile jt; next iteration ds_writes the regs to
// the same LDS image. Removes the per-iteration exposed L2 round trip
// (stage->vmcnt(0)drain->compute chain) that R8's counters identified as
// the stall (MfmaUtil 16.7 + VALU 50 -> 33% no-issue). LDS image, chunk
// mapping, swizzles byte-identical to v8's stage_grp; 2 barriers/iter
// unchanged; ds_writes stride-1 b128 (conflict-free).
// + diag-split softmax: mask cmp+cndmask only on diagonal tiles (wave-
// uniform branch), saves ~32 VALU/tile on the 16-of-17 non-diag tiles.
// ---------------------------------------------------------------------------
__global__ __launch_bounds__(512, 4) void moire_attn9(
    const short* __restrict__ q2, const short* __restrict__ k2,
    const short* __restrict__ v2t, const float* __restrict__ theta,
    short* __restrict__ att)
{
    __shared__ __attribute__((aligned(16))) short Ks[2][64 * 128];  // 32 KB
    __shared__ __attribute__((aligned(16))) short Vt[2][64 * 64];   // 16 KB
    __shared__ __attribute__((aligned(16))) short Ps[8][16 * 64];   // 16 KB

    const int tid = threadIdx.x;
    const int wave = tid >> 6, lane = tid & 63;
    const int quad = lane >> 4, c = lane & 15;
    const int tx = wave >> 2, gw = wave & 3;
    // XCD-chunked bijective swizzle (T1): f%8 = XCD; XCD k gets 4 (h,b) pairs.
    const int f = blockIdx.x + 16 * (blockIdx.y + 16 * blockIdx.z);  // 0..511
    const int w = (f & 7) * 64 + (f >> 3);
    const int p = w & 15;
    const int hb = w >> 4;                    // 0..31
    const int h = hb & 15, b = hb >> 4;
    const int qB = 31 - p;
    const float th = theta[h];

    const short* k2b = k2 + (size_t)(b * Hc + h) * Tc * 128;
    const short* v2b = v2t + (size_t)(b * Hc + h) * Dc * Tc;
    const short* q2b = q2 + (size_t)(b * Hc + h) * Tc * 128;

    // current target q-tile state (group A switches at the transition)
    int qcur = tx ? qB : p;
    int q0 = qcur * 64;
    const int t_l = gw * 16 + c;

    // Q B-frags (n = t): row q0 + t_l, 4 K-chunks of 32
    short8 qf[4];
    {
        const short* qp = q2b + (size_t)(q0 + t_l) * 128;
#pragma unroll
        for (int i = 0; i < 4; ++i)
            qf[i] = *(const short8*)(qp + i * 32 + quad * 8);
    }

    // gate*L2E = cb*cOff - sb*sOff; (cb,sb) = (cos,sin) of th/8*(jt*64 - t_g)
    float x0 = th * 0.125f * (float)(q0 + t_l);
    float cb = __cosf(x0), sb = -__sinf(x0);
    float cOff[4][4], sOff[4][4];
#pragma unroll
    for (int mt = 0; mt < 4; ++mt)
#pragma unroll
        for (int reg = 0; reg < 4; ++reg) {
            float a = th * 0.125f * (float)(mt * 16 + quad * 4 + reg);
            cOff[mt][reg] = __cosf(a) * L2E;
            sOff[mt][reg] = __sinf(a) * L2E;
        }
    const float cD = __cosf(8.f * th), sD = __sinf(8.f * th);  // 64-step rot

    f32x4 oacc[4];
    float lsum = 0.f;
#pragma unroll
    for (int nt = 0; nt < 4; ++nt)
        oacc[nt] = (f32x4){0.f, 0.f, 0.f, 0.f};

    // ---- phase-1 staging (all threads, global_load_lds, dbuf -- v8 verbatim)
    auto stageK_all = [&](int jts, int buf) {
        short* dst = &Ks[buf][0];
        const int s0 = jts * 64;
#pragma unroll
        for (int i = 0; i < 2; ++i) {          // 1024 16B chunks, 2/thread
            int ch = i * 512 + tid;
            int row = ch >> 4, j = ch & 15;
            const short* src = k2b + (size_t)(s0 + row) * 128 + ((j ^ (row & 15)) << 3);
            __builtin_amdgcn_global_load_lds(
                (const __attribute__((address_space(1))) void*)src,
                (__attribute__((address_space(3))) void*)(dst + (i * 512 + wave * 64) * 8),
                16, 0, 0);
        }
    };
    auto stageV_all = [&](int jts, int buf) {
        short* dst = &Vt[buf][0];
        const int s0 = jts * 64;
        int row = tid >> 3, j = tid & 7;       // 512 16B chunks, 1/thread
        const short* src = v2b + (size_t)row * Tc + s0 + ((j ^ (row & 7)) << 3);
        __builtin_amdgcn_global_load_lds(
            (const __attribute__((address_space(1))) void*)src,
            (__attribute__((address_space(3))) void*)(dst + (wave * 64) * 8),
            16, 0, 0);
    };

    // ---- phase-2 T14 reg-staged prefetch (own 256-thread group).
    // Same chunk->(row, swizzled col) image as v8's stage_grp: chunk ch
    // lives at LDS offset ch*16B.
    short8 rK[4], rV[2];
    const int ltid = tid & 255;
    auto pf_load = [&](int jts) {
        const int s0 = jts * 64;
#pragma unroll
        for (int jj = 0; jj < 4; ++jj) {       // K: 1024 chunks, 4/thread
            int ch = jj * 256 + ltid;
            int row = ch >> 4, j = ch & 15;
            rK[jj] = *(const short8*)(k2b + (size_t)(s0 + row) * 128 +
                                      ((j ^ (row & 15)) << 3));
        }
#pragma unroll
        for (int jj = 0; jj < 2; ++jj) {       // V: 512 chunks, 2/thread
            int ch = jj * 256 + ltid;
            int row = ch >> 3, j = ch & 7;
            rV[jj] = *(const short8*)(v2b + (size_t)row * Tc + s0 +
                                      ((j ^ (row & 7)) << 3));
        }
    };
    auto pf_write = [&](int buf) {
        short* dk = &Ks[buf][0];
        short* dv = &Vt[buf][0];
#pragma unroll
        for (int jj = 0; jj < 4; ++jj)
            *(short8*)(dk + (jj * 256 + ltid) * 8) = rK[jj];
#pragma unroll
        for (int jj = 0; jj < 2; ++jj)
            *(short8*)(dv + (jj * 256 + ltid) * 8) = rV[jj];
    };

    // S^T + softmax + Ps write for tile jt from slot buf; rotates base angle.
    auto do_s = [&](int jt, int buf) {
        const short* KsB = &Ks[buf][0];

        f32x4 s_acc[4];
#pragma unroll
        for (int mt = 0; mt < 4; ++mt) {
            f32x4 a = {0.f, 0.f, 0.f, 0.f};
#pragma unroll
            for (int kk = 0; kk < 4; ++kk) {
                short8 kf = *(const short8*)&KsB[(mt * 16 + c) * 128 +
                                                 (((kk * 4 + quad) ^ c) << 3)];
                a = __builtin_amdgcn_mfma_f32_16x16x32_bf16(kf, qf[kk], a, 0, 0, 0);
            }
            s_acc[mt] = a;
        }

        if (jt == qcur) {                      // diagonal tile: masked (wave-uniform)
#pragma unroll
            for (int mt = 0; mt < 4; ++mt) {
                float pv[4];
#pragma unroll
                for (int reg = 0; reg < 4; ++reg) {
                    float g2 = cb * cOff[mt][reg] - sb * sOff[mt][reg];
                    float arg = fmaf(s_acc[mt][reg], g2, -SM_M * L2E);
                    if ((mt * 16 + quad * 4 + reg) > t_l) arg = -1e30f;
                    pv[reg] = exp2f(arg);
                }
                lsum += (pv[0] + pv[1]) + (pv[2] + pv[3]);
                uint2 pk = {pack2bf_fast(pv[0], pv[1]), pack2bf_fast(pv[2], pv[3])};
                int slot = ((mt * 2 + (quad >> 1)) ^ (c & 7));
                *(uint2*)&Ps[wave][c * 64 + slot * 8 + (quad & 1) * 4] = pk;
            }
        } else {                               // off-diagonal: no mask ops
#pragma unroll
            for (int mt = 0; mt < 4; ++mt) {
                float pv[4];
#pragma unroll
                for (int reg = 0; reg < 4; ++reg) {
                    float g2 = cb * cOff[mt][reg] - sb * sOff[mt][reg];
                    float arg = fmaf(s_acc[mt][reg], g2, -SM_M * L2E);
                    pv[reg] = exp2f(arg);
                }
                lsum += (pv[0] + pv[1]) + (pv[2] + pv[3]);
                uint2 pk = {pack2bf_fast(pv[0], pv[1]), pack2bf_fast(pv[2], pv[3])};
                int slot = ((mt * 2 + (quad >> 1)) ^ (c & 7));
                *(uint2*)&Ps[wave][c * 64 + slot * 8 + (quad & 1) * 4] = pk;
            }
        }

        float ncb = cb * cD - sb * sD;         // advance one 64-tile
        sb = sb * cD + cb * sD;
        cb = ncb;
    };

    auto do_pv = [&](int buf) {
        const short* VtB = &Vt[buf][0];
        short8 pf[2];
#pragma unroll
        for (int kk = 0; kk < 2; ++kk)
            pf[kk] = *(const short8*)&Ps[wave][c * 64 +
                         (((kk * 4 + quad) ^ (c & 7)) << 3)];
#pragma unroll
        for (int nt = 0; nt < 4; ++nt)
#pragma unroll
            for (int kk = 0; kk < 2; ++kk) {
                short8 vf = *(const short8*)&VtB[(nt * 16 + c) * 64 +
                             (((kk * 4 + quad) ^ (c & 7)) << 3)];
                oacc[nt] = __builtin_amdgcn_mfma_f32_16x16x32_bf16(
                    pf[kk], vf, oacc[nt], 0, 0, 0);
            }
    };

    auto write_out = [&]() {
        float l = lsum;
        l += __shfl_xor(l, 16);
        l += __shfl_xor(l, 32);
        float il = 1.f / l;
        float ilr[4];
#pragma unroll
        for (int reg = 0; reg < 4; ++reg)
            ilr[reg] = __shfl(il, quad * 4 + reg);
#pragma unroll
        for (int reg = 0; reg < 4; ++reg) {
            int t_o = q0 + gw * 16 + quad * 4 + reg;
#pragma unroll
            for (int nt = 0; nt < 4; ++nt)
                att[(size_t)(b * Tc + t_o) * Cc + h * Dc + nt * 16 + c] =
                    f2bf(oacc[nt][reg] * ilr[reg]);
        }
    };

    // ---- phase 1: jt = 0..p, shared staging, prefetch jt+1 (v6 verbatim)
    stageK_all(0, 0); stageV_all(0, 0);
    for (int jt = 0; jt <= p; ++jt) {
        __syncthreads();
        stageK_all(jt + 1, (jt + 1) & 1);      // jt==p stages B's first ph2 tile
        stageV_all(jt + 1, (jt + 1) & 1);
        do_s(jt, jt & 1);
        do_pv(jt & 1);
    }
    const int slotB = (p + 1) & 1, slotA = slotB ^ 1;

    // ---- transition
    __syncthreads();                           // tile p+1 landed; phase-1 reads done
    if (p < 15) pf_load(tx ? (p + 2) : 17);    // T14: first ph2 tile -> regs,
                                               // latency hides under transition work
    if (tx == 0) {
        write_out();                           // qA complete
#pragma unroll
        for (int nt = 0; nt < 4; ++nt)
            oacc[nt] = (f32x4){0.f, 0.f, 0.f, 0.f};
        lsum = 0.f;
        qcur = qB; q0 = qB * 64;
        const short* qp = q2b + (size_t)(q0 + t_l) * 128;
#pragma unroll
        for (int i = 0; i < 4; ++i)
            qf[i] = *(const short8*)(qp + i * 32 + quad * 8);
        float a = th * 0.125f * (1088.f - (float)(q0 + t_l));   // base @ jt=17
        __sincosf(a, &sb, &cb);
    } else {
        do_s(p + 1, slotB);                    // diag here only when p==15
        do_pv(slotB);
    }

    // ---- phase 2: 15-p iterations, both groups busy, reg-staged prefetch.
    // Per iter: barrier (WAR on slot) -> ds_write prefetched regs (compiler
    // waits the loads) -> barrier (visible) -> issue next prefetch -> compute.
    // The global-load latency for jt+1 hides under do_s+do_pv of jt.
    for (int i = 0; i <= 14 - p; ++i) {
        const int jt = tx ? (p + 2 + i) : (17 + i);
        const int sl = tx ? slotB : slotA;
        __syncthreads();                       // WAR: previous reads of slot done
        pf_write(sl);
        __syncthreads();                       // writes visible
        if (i < 14 - p) pf_load(jt + 1);
        do_s(jt, sl);
        do_pv(sl);
    }

    // ---- combine qB partials: A -> LDS (reuse Ks), B adds + writes
    __syncthreads();
    float* Cmb = (float*)&Ks[0][0];            // 256 x 20 f32 = 20 KB of 32 KB
    if (tx == 0) {
        float* pp = Cmb + (size_t)(gw * 64 + lane) * 20;
#pragma unroll
        for (int nt = 0; nt < 4; ++nt) *(f32x4*)(pp + nt * 4) = oacc[nt];
        pp[16] = lsum;
    }
    __syncthreads();
    if (tx == 1) {
        const float* pp = Cmb + (size_t)(gw * 64 + lane) * 20;
#pragma unroll
        for (int nt = 0; nt < 4; ++nt)
            oacc[nt] += *(const f32x4*)(pp + nt * 4);
        lsum += pp[16];
        write_out();
    }
}

// ---------------------------------------------------------------------------
extern "C" void kernel_launch(void* const* d_in, const int* in_sizes, int n_in,
                              void* d_out, int out_size, void* d_ws, size_t ws_size,
                              hipStream_t stream)
{
    const float* x     = (const float*)d_in[0];
    const float* Wq    = (const float*)d_in[1];
    const float* Wk    = (const float*)d_in[2];
    const float* Wv    = (const float*)d_in[3];
    const float* Wo    = (const float*)d_in[4];
    const float* theta = (const float*)d_in[5];
    float* out = (float*)d_out;

    const int M = Bc * Tc;                 // 4096
    char* ws = (char*)d_ws;
    const size_t MB = 1 << 20;
    short* xb   = (short*)(ws);             // [0,8)   x bf16
    short* Bqk  = (short*)(ws + 8 * MB);    // [8,16)  permuted [Wq'|Wk']^T bf16
    short* Wvt  = (short*)(ws + 16 * MB);   // [16,18)
    short* Wot  = (short*)(ws + 18 * MB);   // [18,20)
    short* v2t  = (short*)(ws + 28 * MB);   // [28,36) bf16 (B,H,D,T)
    short* attb = (short*)(ws + 36 * MB);   // [36,44)
    short* q2   = (short*)(ws + 44 * MB);   // [44,60) bf16 (B,H,T,128)
    short* k2   = (short*)d_out;            // 16 MB   bf16 (B,H,T,128) until final gemm

    xconv<<<(size_t)M * Cc / 1024, 256, 0, stream>>>(x, xb);
    wtrans_qk<<<dim3(2048 / 64, Cc / 64, 2), 256, 0, stream>>>(Wq, Wk, Bqk);
    wtrans2<<<dim3(Cc / 64, Cc / 64, 2), 256, 0, stream>>>(Wv, Wo, Wvt);

    // fused QK projection + moire transform (256^2 8-phase, writes q2, k2)
    gemm256_qk<<<dim3(4096 / 256, M / 256), 512, 0, stream>>>(xb, Bqk, q2, k2);
    // fused V projection + head-transpose (writes v2t directly)
    gemm_v2t<<<dim3(Cc / 128, M / 128), 512, 0, stream>>>(xb, Wvt, v2t);

    moire_attn9<<<dim3(16, Hc, Bc), 512, 0, stream>>>(q2, k2, v2t, theta, attb);

    gemm_bt_mfma<0><<<dim3(Cc / 128, M / 128), 512, 0, stream>>>(
        attb, Wot, out, nullptr, M, Cc, Cc);
}

// Round 10
// 294.280 us; speedup vs baseline: 1.3952x; 1.3952x over previous
//
#include <hip/hip_runtime.h>
#include <hip/hip_bf16.h>
#include <math.h>

// Problem constants
#define Bc 2
#define Tc 2048
#define Cc 1024
#define Hc 16
#define Dc 64
// SCALE = 1/8, GAMMA = 8

typedef __attribute__((ext_vector_type(8))) short short8;   // 8 bf16 (4 VGPRs)
typedef __attribute__((ext_vector_type(4))) float f32x4;    // MFMA C/D frag

#define L2E 1.44269504088896f
#define SM_M 20.0f   // fixed softmax shift; |scores| << 20 (std ~0.3)

__device__ __forceinline__ short f2bf(float x) {
    unsigned u = __float_as_uint(x);
    u += 0x7fff + ((u >> 16) & 1);      // RNE
    return (short)(u >> 16);
}
// pack two non-negative floats to bf16 pair (round-half-up) in 3 VALU ops
__device__ __forceinline__ unsigned pack2bf_fast(float a, float b) {
    unsigned ua = __float_as_uint(a) + 0x8000u;
    unsigned ub = __float_as_uint(b) + 0x8000u;
    return __builtin_amdgcn_perm(ub, ua, 0x07060302);  // (ua>>16)|(ub&0xffff0000)
}
// fast softplus: 2 HW transcendentals, ~1e-6 rel err (invisible at bf16)
__device__ __forceinline__ float softplus_fast(float a) {
    return fmaxf(a, 0.f) + __logf(1.f + __expf(-fabsf(a)));
}

// ---------------------------------------------------------------------------
// 256x256 8-phase bf16 GEMM with fused moire-QK epilogue (m201 template).
// R6: + XCD-aware bijective block swizzle (T1).  (unchanged from R8-verified)
// ---------------------------------------------------------------------------
#define RDA(BUF, MH) do {                                                      \
    const short* Ah_ = &Al[BUF][MH][0];                                        \
    _Pragma("unroll") for (int mt_ = 0; mt_ < 4; ++mt_) {                      \
        af[mt_][0] = *(const short8*)&Ah_[(wm*64 + mt_*16 + c)*64 + rsw0];     \
        af[mt_][1] = *(const short8*)&Ah_[(wm*64 + mt_*16 + c)*64 + rsw1];     \
    } } while (0)

#define RDB(BUF, NH) do {                                                      \
    const short* Bh_ = &Bl[BUF][NH][0];                                        \
    _Pragma("unroll") for (int nf_ = 0; nf_ < 2; ++nf_) {                      \
        bfr[NH][nf_][0] = *(const short8*)&Bh_[(wn*32 + nf_*16 + c)*64 + rsw0];\
        bfr[NH][nf_][1] = *(const short8*)&Bh_[(wn*32 + nf_*16 + c)*64 + rsw1];\
    } } while (0)

#define MMQ(MH, NH) do {                                                       \
    _Pragma("unroll") for (int mt_ = 0; mt_ < 4; ++mt_)                        \
    _Pragma("unroll") for (int nf_ = 0; nf_ < 2; ++nf_) {                      \
        acc[MH][NH][mt_][nf_] = __builtin_amdgcn_mfma_f32_16x16x32_bf16(       \
            af[mt_][0], bfr[NH][nf_][0], acc[MH][NH][mt_][nf_], 0, 0, 0);      \
        acc[MH][NH][mt_][nf_] = __builtin_amdgcn_mfma_f32_16x16x32_bf16(       \
            af[mt_][1], bfr[NH][nf_][1], acc[MH][NH][mt_][nf_], 0, 0, 0);      \
    } } while (0)

#define BARw asm volatile("s_barrier" ::: "memory")
#define VMW6 asm volatile("s_waitcnt vmcnt(6)" ::: "memory")
#define VMW0 asm volatile("s_waitcnt vmcnt(0)" ::: "memory")
#define PRIO1 __builtin_amdgcn_s_setprio(1)
#define PRIO0 __builtin_amdgcn_s_setprio(0)

__global__ __launch_bounds__(512, 2) void gemm256_qk(
    const short* __restrict__ A, const short* __restrict__ Bt,
    short* __restrict__ q2, short* __restrict__ k2)
{
    __shared__ __attribute__((aligned(16))) short Al[2][2][128 * 64];  // 64 KB
    __shared__ __attribute__((aligned(16))) short Bl[2][2][128 * 64];  // 64 KB

    const int tid = threadIdx.x;
    const int wave = tid >> 6, lane = tid & 63;
    const int quad = lane >> 4, c = lane & 15;
    const int wm = wave >> 2, wn = wave & 3;          // 2M x 4N waves
    // XCD-chunked bijective swizzle: f%8 = XCD (round-robin dispatch);
    // XCD k owns w in [32k,32k+32) = 2 full grid rows -> A-panel L2 reuse.
    const int f = blockIdx.x + 16 * blockIdx.y;       // 0..255
    const int w = (f & 7) * 32 + (f >> 3);
    const int bx = w & 15, by = w >> 4;
    const int m0 = by * 256, n0 = bx * 256;

    // swizzled ds_read byte-slot (shorts): (ks*64 + quad*16) ^ ((c&7)<<4)
    const int rsw0 = ((quad * 16) ^ ((c & 7) << 4)) >> 1;
    const int rsw1 = ((64 + quad * 16) ^ ((c & 7) << 4)) >> 1;

    f32x4 acc[2][2][4][2];
#pragma unroll
    for (int a0 = 0; a0 < 2; ++a0)
#pragma unroll
        for (int a1 = 0; a1 < 2; ++a1)
#pragma unroll
            for (int a2 = 0; a2 < 4; ++a2)
#pragma unroll
                for (int a3 = 0; a3 < 2; ++a3)
                    acc[a0][a1][a2][a3] = (f32x4){0.f, 0.f, 0.f, 0.f};

    short8 af[4][2];        // A-frags: 4 m-frags x 2 k-steps (32 VGPR)
    short8 bfr[2][2][2];    // B-frags: [nh][nf][ks] both halves kept (32 VGPR)

    auto stA = [&](int kt, int hh) {
        short* dstb = &Al[kt & 1][hh][0];
#pragma unroll
        for (int j = 0; j < 2; ++j) {
            int ch = j * 512 + tid;
            int row = ch >> 3;
            int os = ((((ch & 7) << 4) ^ ((row & 7) << 4)) >> 1);
            const short* src = A + (size_t)(m0 + hh * 128 + row) * 1024 + kt * 64 + os;
            __builtin_amdgcn_global_load_lds(
                (const __attribute__((address_space(1))) void*)src,
                (__attribute__((address_space(3))) void*)(dstb + (j * 512 + wave * 64) * 8),
                16, 0, 0);
        }
    };
    auto stB = [&](int kt, int hh) {
        short* dstb = &Bl[kt & 1][hh][0];
#pragma unroll
        for (int j = 0; j < 2; ++j) {
            int ch = j * 512 + tid;
            int row = ch >> 3;
            int os = ((((ch & 7) << 4) ^ ((row & 7) << 4)) >> 1);
            const short* src = Bt + (size_t)(n0 + hh * 128 + row) * 1024 + kt * 64 + os;
            __builtin_amdgcn_global_load_lds(
                (const __attribute__((address_space(1))) void*)src,
                (__attribute__((address_space(3))) void*)(dstb + (j * 512 + wave * 64) * 8),
                16, 0, 0);
        }
    };

    // prologue: tile0 fully + tile1 {Bh0, Ah0, Bh1}; Ah1(1) comes at p1 of i=0.
    stB(0, 0); stA(0, 0); stB(0, 1); stA(0, 1); stB(1, 0); stA(1, 0); stB(1, 1);
    VMW6;          // oldest 8 loads (= all of tile 0) landed
    BARw;

    // K = 1024 -> 16 K-tiles -> 8 iterations of 2 tiles (buf0 = even tile).
    for (int i = 0; i < 8; ++i) {
        const int e = 2 * i;
        const bool more = (i < 7);
        // ---- group e (buf 0) ----
        RDA(0, 0); RDB(0, 0);                 // p1: 12 ds_reads
        stA(e + 1, 1);                        //     stage Ah1(odd tile)
        BARw; PRIO1; MMQ(0, 0); PRIO0; BARw;
        RDB(0, 1);                            // p2: 4 ds_reads (A kept)
        if (more) stB(e + 2, 0);
        BARw; PRIO1; MMQ(0, 1); PRIO0; BARw;
        RDA(0, 1);                            // p3: 8 ds_reads (B0 kept)
        if (more) stA(e + 2, 0);
        BARw; PRIO1; MMQ(1, 0); PRIO0; BARw;
        if (more) stB(e + 2, 1);              // p4: no ds_reads (A,B1 kept)
        BARw; PRIO1; MMQ(1, 1); PRIO0;
        if (more) { VMW6; } else { VMW0; }
        BARw;
        // ---- group o (buf 1) ----
        RDA(1, 0); RDB(1, 0);                 // p5
        if (more) stA(e + 2, 1);
        BARw; PRIO1; MMQ(0, 0); PRIO0; BARw;
        RDB(1, 1);                            // p6
        if (more) stB(e + 3, 0);
        BARw; PRIO1; MMQ(0, 1); PRIO0; BARw;
        RDA(1, 1);                            // p7
        if (more) stA(e + 3, 0);
        BARw; PRIO1; MMQ(1, 0); PRIO0; BARw;
        if (more) stB(e + 3, 1);              // p8
        BARw; PRIO1; MMQ(1, 1); PRIO0;
        if (more) { VMW6; } else { VMW0; }
        BARw;
    }

    // moire epilogue: cols of this lane: n = n0 + nh*128 + wn*32 + nf*16 + c
    const int d = wn * 16 + c;
#pragma unroll
    for (int mh = 0; mh < 2; ++mh) {
#pragma unroll
        for (int nh = 0; nh < 2; ++nh) {
            const int g = 2 * bx + nh;
            const int isK = g >> 4;
            const int hh = g & 15;
            const float scl = isK ? 1.f : 0.125f;
            short* dst = isK ? k2 : q2;       // (B,H,T,128)
#pragma unroll
            for (int mt = 0; mt < 4; ++mt) {
#pragma unroll
                for (int reg = 0; reg < 4; ++reg) {
                    int m = m0 + mh * 128 + wm * 64 + mt * 16 + quad * 4 + reg;
                    int bb = m >> 11, tt = m & (Tc - 1);
                    size_t base = (((size_t)bb * Hc + hh) * Tc + tt) * 128;
                    float amp = acc[mh][nh][mt][0][reg];
                    float ph  = acc[mh][nh][mt][1][reg];
                    float sp = softplus_fast(amp) * scl;
                    float sn, cs;
                    __sincosf(ph, &sn, &cs);
                    dst[base + d]      = f2bf(sp * cs);
                    dst[base + d + 64] = f2bf(sp * sn);
                }
            }
        }
    }
}

// ---------------------------------------------------------------------------
// bf16 MFMA GEMM, 512-thread variant (R5). 4M x 2N waves, 32x64 per wave.
// ---------------------------------------------------------------------------
template <int EPI>
__global__ __launch_bounds__(512) void gemm_bt_mfma(
    const short* __restrict__ A, const short* __restrict__ Bt,
    float* __restrict__ Cf, short* __restrict__ Cb,
    int M, int N, int K)
{
    __shared__ __attribute__((aligned(16))) short As[128 * 32];
    __shared__ __attribute__((aligned(16))) short Bs[128 * 32];

    const int tid = threadIdx.x;
    const int lane = tid & 63;
    const int wave = tid >> 6;
    const int quad = lane >> 4, c = lane & 15;
    const int wm = wave >> 1, wn = wave & 1;          // 4M x 2N waves
    const int m0 = blockIdx.y * 128, n0 = blockIdx.x * 128;

    const int srow = tid >> 2;                        // 0..127
    const int scol = (tid & 3) * 8;
    const short* Ag = A  + (size_t)(m0 + srow) * K + scol;
    const short* Bg = Bt + (size_t)(n0 + srow) * K + scol;
    short* AsW = As + tid * 8;
    short* BsW = Bs + tid * 8;

    f32x4 acc[2][4];
#pragma unroll
    for (int i = 0; i < 2; ++i)
#pragma unroll
        for (int j = 0; j < 4; ++j)
            acc[i][j] = (f32x4){0.f, 0.f, 0.f, 0.f};

    for (int k0 = 0; k0 < K; k0 += 32) {
        __syncthreads();
        __builtin_amdgcn_global_load_lds(
            (const __attribute__((address_space(1))) void*)(Ag + k0),
            (__attribute__((address_space(3))) void*)AsW, 16, 0, 0);
        __builtin_amdgcn_global_load_lds(
            (const __attribute__((address_space(1))) void*)(Bg + k0),
            (__attribute__((address_space(3))) void*)BsW, 16, 0, 0);
        __syncthreads();

        short8 af[2], bf[4];
#pragma unroll
        for (int mt = 0; mt < 2; ++mt)
            af[mt] = *(const short8*)&As[(wm * 32 + mt * 16 + c) * 32 + quad * 8];
#pragma unroll
        for (int nt = 0; nt < 4; ++nt)
            bf[nt] = *(const short8*)&Bs[(wn * 64 + nt * 16 + c) * 32 + quad * 8];
#pragma unroll
        for (int mt = 0; mt < 2; ++mt)
#pragma unroll
            for (int nt = 0; nt < 4; ++nt)
                acc[mt][nt] = __builtin_amdgcn_mfma_f32_16x16x32_bf16(
                    af[mt], bf[nt], acc[mt][nt], 0, 0, 0);
    }

#pragma unroll
    for (int mt = 0; mt < 2; ++mt) {
#pragma unroll
        for (int reg = 0; reg < 4; ++reg) {
            size_t row = m0 + wm * 32 + mt * 16 + quad * 4 + reg;
#pragma unroll
            for (int nt = 0; nt < 4; ++nt) {
                size_t col = n0 + wn * 64 + nt * 16 + c;
                if (EPI == 1) Cb[row * N + col] = f2bf(acc[mt][nt][reg]);
                else          Cf[row * N + col] = acc[mt][nt][reg];
            }
        }
    }
}

// ---------------------------------------------------------------------------
// V projection fused with head-transpose: v2t[(b,h,d),t] = (xb @ Wvt^T).
// 512-thread variant (R5).
// ---------------------------------------------------------------------------
__global__ __launch_bounds__(512) void gemm_v2t(
    const short* __restrict__ A, const short* __restrict__ Bt,
    short* __restrict__ v2t)
{
    __shared__ __attribute__((aligned(16))) short As[128 * 32];
    __shared__ __attribute__((aligned(16))) short Bs[128 * 32];
    __shared__ __attribute__((aligned(16))) short tile[128 * 136];  // [n][t]

    const int K = Cc;
    const int tid = threadIdx.x;
    const int lane = tid & 63;
    const int wave = tid >> 6;
    const int quad = lane >> 4, c = lane & 15;
    const int wm = wave >> 1, wn = wave & 1;          // 4M x 2N waves
    const int m0 = blockIdx.y * 128, n0 = blockIdx.x * 128;

    const int srow = tid >> 2;
    const int scol = (tid & 3) * 8;
    const short* Ag = A  + (size_t)(m0 + srow) * K + scol;
    const short* Bg = Bt + (size_t)(n0 + srow) * K + scol;
    short* AsW = As + tid * 8;
    short* BsW = Bs + tid * 8;

    f32x4 acc[2][4];
#pragma unroll
    for (int i = 0; i < 2; ++i)
#pragma unroll
        for (int j = 0; j < 4; ++j)
            acc[i][j] = (f32x4){0.f, 0.f, 0.f, 0.f};

    for (int k0 = 0; k0 < K; k0 += 32) {
        __syncthreads();
        __builtin_amdgcn_global_load_lds(
            (const __attribute__((address_space(1))) void*)(Ag + k0),
            (__attribute__((address_space(3))) void*)AsW, 16, 0, 0);
        __builtin_amdgcn_global_load_lds(
            (const __attribute__((address_space(1))) void*)(Bg + k0),
            (__attribute__((address_space(3))) void*)BsW, 16, 0, 0);
        __syncthreads();

        short8 af[2], bf[4];
#pragma unroll
        for (int mt = 0; mt < 2; ++mt)
            af[mt] = *(const short8*)&As[(wm * 32 + mt * 16 + c) * 32 + quad * 8];
#pragma unroll
        for (int nt = 0; nt < 4; ++nt)
            bf[nt] = *(const short8*)&Bs[(wn * 64 + nt * 16 + c) * 32 + quad * 8];
#pragma unroll
        for (int mt = 0; mt < 2; ++mt)
#pragma unroll
            for (int nt = 0; nt < 4; ++nt)
                acc[mt][nt] = __builtin_amdgcn_mfma_f32_16x16x32_bf16(
                    af[mt], bf[nt], acc[mt][nt], 0, 0, 0);
    }

    // epilogue: stash transposed into LDS [n][t]
#pragma unroll
    for (int mt = 0; mt < 2; ++mt)
#pragma unroll
        for (int reg = 0; reg < 4; ++reg) {
            int tl = wm * 32 + mt * 16 + quad * 4 + reg;
#pragma unroll
            for (int nt = 0; nt < 4; ++nt)
                tile[(wn * 64 + nt * 16 + c) * 136 + tl] = f2bf(acc[mt][nt][reg]);
        }
    __syncthreads();

    const int b = m0 >> 11, tl0 = m0 & (Tc - 1);
#pragma unroll
    for (int i = 0; i < 4; ++i) {
        int n = i * 32 + (tid >> 4);
        int t8 = (tid & 15) * 8;
        int ng = n0 + n, h = ng >> 6, d = ng & 63;
        *(short8*)&v2t[(((size_t)b * Hc + h) * Dc + d) * Tc + tl0 + t8] =
            *(const short8*)&tile[n * 136 + t8];
    }
}

// ---------------------------------------------------------------------------
__global__ __launch_bounds__(256) void xconv(const float* __restrict__ x,
                                             short* __restrict__ xb)
{
    int idx = blockIdx.x * 256 + threadIdx.x;
    float4 v = *(const float4*)&x[(size_t)idx * 4];
    short4 o = {f2bf(v.x), f2bf(v.y), f2bf(v.z), f2bf(v.w)};
    *(short4*)&xb[(size_t)idx * 4] = o;
}

// ---------------------------------------------------------------------------
// Wq|Wk transpose-convert with the gemm256_qk row permutation.
// ---------------------------------------------------------------------------
__global__ __launch_bounds__(256) void wtrans_qk(const float* __restrict__ Wq,
                                                 const float* __restrict__ Wk,
                                                 short* __restrict__ Bt)
{
    __shared__ short tile[64][80];
    const int n0 = blockIdx.x * 64, k0 = blockIdx.y * 64;
    const int half = blockIdx.z;
    const float* W = half ? Wk : Wq;
    const int tid = threadIdx.x;
#pragma unroll
    for (int i = 0; i < 4; ++i) {
        int e = i * 256 + tid;
        int k = e >> 4, n4 = (e & 15) * 4;
        float4 v = *(const float4*)&W[(size_t)(k0 + k) * 2048 + n0 + n4];
        tile[k][n4]     = f2bf(v.x);
        tile[k][n4 + 1] = f2bf(v.y);
        tile[k][n4 + 2] = f2bf(v.z);
        tile[k][n4 + 3] = f2bf(v.w);
    }
    __syncthreads();
#pragma unroll
    for (int i = 0; i < 16; ++i) {
        int e = i * 256 + tid;
        int n = e >> 6, k = e & 63;
        int ng = n0 + n;
        int sub = ng >> 10, hh = (ng >> 6) & 15, dd = ng & 63;
        int r = (half * 16 + hh) * 128 + (dd >> 4) * 32 + sub * 16 + (dd & 15);
        Bt[(size_t)r * Cc + k0 + k] = tile[k][n];
    }
}

// ---------------------------------------------------------------------------
__global__ __launch_bounds__(256) void wtrans2(const float* __restrict__ Wv,
                                               const float* __restrict__ Wo,
                                               short* __restrict__ WtBase)
{
    __shared__ short tile[64][80];
    const int n0 = blockIdx.x * 64, k0 = blockIdx.y * 64;
    const float* W = blockIdx.z ? Wo : Wv;
    short* Wt = WtBase + (size_t)blockIdx.z * Cc * Cc;
    const int tid = threadIdx.x;
#pragma unroll
    for (int i = 0; i < 4; ++i) {
        int e = i * 256 + tid;
        int k = e >> 4, n4 = (e & 15) * 4;
        float4 v = *(const float4*)&W[(size_t)(k0 + k) * Cc + n0 + n4];
        tile[k][n4]     = f2bf(v.x);
        tile[k][n4 + 1] = f2bf(v.y);
        tile[k][n4 + 2] = f2bf(v.z);
        tile[k][n4 + 3] = f2bf(v.w);
    }
    __syncthreads();
#pragma unroll
    for (int i = 0; i < 16; ++i) {
        int e = i * 256 + tid;
        int n = e >> 6, k = e & 63;
        Wt[(size_t)(n0 + n) * Cc + k0 + k] = tile[k][n];
    }
}

// ---------------------------------------------------------------------------
// MFMA flash attention v10 = R8-verified v8 (+XCD swizzle, FETCH 124->22MB)
// + T14 phase-2 prefetch, codegen-safe retry (R10).
// R9 lesson: lambda-captured register ARRAYS living across barriers spill
// to scratch (WRITE_SIZE 237MB, VGPR flat at 64). v10 uses six NAMED short8
// scalars + textual macros; all indices compile-time constant; per-chunk
// base pointers precomputed. Same LDS image/swizzles as v8's stage_grp.
// Mechanism (T14): issue 6 global loads for tile jt+1 BEFORE computing
// tile jt; ds_write them next iteration (loads have ~600cy to land) --
// removes the per-iteration exposed stage->vmcnt(0)drain->compute chain
// that R8's counters identified (MfmaUtil 16.7 + VALU 50 -> 33% no-issue).
// do_s reverted to v8's exact single version (one change per round).
// ---------------------------------------------------------------------------
__global__ __launch_bounds__(512, 4) void moire_attn10(
    const short* __restrict__ q2, const short* __restrict__ k2,
    const short* __restrict__ v2t, const float* __restrict__ theta,
    short* __restrict__ att)
{
    __shared__ __attribute__((aligned(16))) short Ks[2][64 * 128];  // 32 KB
    __shared__ __attribute__((aligned(16))) short Vt[2][64 * 64];   // 16 KB
    __shared__ __attribute__((aligned(16))) short Ps[8][16 * 64];   // 16 KB

    const int tid = threadIdx.x;
    const int wave = tid >> 6, lane = tid & 63;
    const int quad = lane >> 4, c = lane & 15;
    const int tx = wave >> 2, gw = wave & 3;
    // XCD-chunked bijective swizzle (T1): f%8 = XCD; XCD k gets 4 (h,b) pairs.
    const int f = blockIdx.x + 16 * (blockIdx.y + 16 * blockIdx.z);  // 0..511
    const int w = (f & 7) * 64 + (f >> 3);
    const int p = w & 15;
    const int hb = w >> 4;                    // 0..31
    const int h = hb & 15, b = hb >> 4;
    const int qB = 31 - p;
    const float th = theta[h];

    const short* k2b = k2 + (size_t)(b * Hc + h) * Tc * 128;
    const short* v2b = v2t + (size_t)(b * Hc + h) * Dc * Tc;
    const short* q2b = q2 + (size_t)(b * Hc + h) * Tc * 128;

    // current target q-tile state (group A switches at the transition)
    int qcur = tx ? qB : p;
    int q0 = qcur * 64;
    const int t_l = gw * 16 + c;

    // Q B-frags (n = t): row q0 + t_l, 4 K-chunks of 32
    short8 qf[4];
    {
        const short* qp = q2b + (size_t)(q0 + t_l) * 128;
#pragma unroll
        for (int i = 0; i < 4; ++i)
            qf[i] = *(const short8*)(qp + i * 32 + quad * 8);
    }

    // gate*L2E = cb*cOff - sb*sOff; (cb,sb) = (cos,sin) of th/8*(jt*64 - t_g)
    float x0 = th * 0.125f * (float)(q0 + t_l);
    float cb = __cosf(x0), sb = -__sinf(x0);
    float cOff[4][4], sOff[4][4];
#pragma unroll
    for (int mt = 0; mt < 4; ++mt)
#pragma unroll
        for (int reg = 0; reg < 4; ++reg) {
            float a = th * 0.125f * (float)(mt * 16 + quad * 4 + reg);
            cOff[mt][reg] = __cosf(a) * L2E;
            sOff[mt][reg] = __sinf(a) * L2E;
        }
    const float cD = __cosf(8.f * th), sD = __sinf(8.f * th);  // 64-step rot

    f32x4 oacc[4];
    float lsum = 0.f;
#pragma unroll
    for (int nt = 0; nt < 4; ++nt)
        oacc[nt] = (f32x4){0.f, 0.f, 0.f, 0.f};

    // ---- phase-1 staging (all threads, global_load_lds, dbuf -- v8 verbatim)
    auto stageK_all = [&](int jts, int buf) {
        short* dst = &Ks[buf][0];
        const int s0 = jts * 64;
#pragma unroll
        for (int i = 0; i < 2; ++i) {          // 1024 16B chunks, 2/thread
            int ch = i * 512 + tid;
            int row = ch >> 4, j = ch & 15;
            const short* src = k2b + (size_t)(s0 + row) * 128 + ((j ^ (row & 15)) << 3);
            __builtin_amdgcn_global_load_lds(
                (const __attribute__((address_space(1))) void*)src,
                (__attribute__((address_space(3))) void*)(dst + (i * 512 + wave * 64) * 8),
                16, 0, 0);
        }
    };
    auto stageV_all = [&](int jts, int buf) {
        short* dst = &Vt[buf][0];
        const int s0 = jts * 64;
        int row = tid >> 3, j = tid & 7;       // 512 16B chunks, 1/thread
        const short* src = v2b + (size_t)row * Tc + s0 + ((j ^ (row & 7)) << 3);
        __builtin_amdgcn_global_load_lds(
            (const __attribute__((address_space(1))) void*)src,
            (__attribute__((address_space(3))) void*)(dst + (wave * 64) * 8),
            16, 0, 0);
    };

    // ---- phase-2 T14 prefetch state: NAMED scalars (R9 lesson: no arrays,
    // no lambda capture). Per-chunk base pointers precomputed; PF_LOAD adds
    // the tile offset (K tile stride 64*128 shorts, V tile stride 64 shorts).
    const int ltid = tid & 255;
    short8 rK0, rK1, rK2, rK3, rV0, rV1;
    const short* pK0; const short* pK1; const short* pK2; const short* pK3;
    const short* pV0; const short* pV1;
    {
        int ch0 = ltid,        r0 = ch0 >> 4;
        int ch1 = 256 + ltid,  r1 = ch1 >> 4;
        int ch2 = 512 + ltid,  r2 = ch2 >> 4;
        int ch3 = 768 + ltid,  r3 = ch3 >> 4;
        pK0 = k2b + (size_t)r0 * 128 + (((ch0 & 15) ^ (r0 & 15)) << 3);
        pK1 = k2b + (size_t)r1 * 128 + (((ch1 & 15) ^ (r1 & 15)) << 3);
        pK2 = k2b + (size_t)r2 * 128 + (((ch2 & 15) ^ (r2 & 15)) << 3);
        pK3 = k2b + (size_t)r3 * 128 + (((ch3 & 15) ^ (r3 & 15)) << 3);
        int cv0 = ltid,        rv0 = cv0 >> 3;
        int cv1 = 256 + ltid,  rv1 = cv1 >> 3;
        pV0 = v2b + (size_t)rv0 * Tc + (((cv0 & 7) ^ (rv0 & 7)) << 3);
        pV1 = v2b + (size_t)rv1 * Tc + (((cv1 & 7) ^ (rv1 & 7)) << 3);
    }
#define PF_LOAD(JTS) do {                                                     \
    const size_t ok_ = (size_t)(JTS) * 8192;                                  \
    const int ov_ = (JTS) * 64;                                               \
    rK0 = *(const short8*)(pK0 + ok_);                                        \
    rK1 = *(const short8*)(pK1 + ok_);                                        \
    rK2 = *(const short8*)(pK2 + ok_);                                        \
    rK3 = *(const short8*)(pK3 + ok_);                                        \
    rV0 = *(const short8*)(pV0 + ov_);                                        \
    rV1 = *(const short8*)(pV1 + ov_); } while (0)
#define PF_WRITE(SL) do {                                                     \
    short* dk_ = &Ks[SL][0];                                                  \
    short* dv_ = &Vt[SL][0];                                                  \
    *(short8*)(dk_ + (size_t)ltid * 8)         = rK0;                         \
    *(short8*)(dk_ + (size_t)(256 + ltid) * 8) = rK1;                         \
    *(short8*)(dk_ + (size_t)(512 + ltid) * 8) = rK2;                         \
    *(short8*)(dk_ + (size_t)(768 + ltid) * 8) = rK3;                         \
    *(short8*)(dv_ + (size_t)ltid * 8)         = rV0;                         \
    *(short8*)(dv_ + (size_t)(256 + ltid) * 8) = rV1; } while (0)

    // S^T + softmax + Ps write for tile jt from slot buf; rotates base angle.
    auto do_s = [&](int jt, int buf) {
        const short* KsB = &Ks[buf][0];
        const bool diag = (jt == qcur);

        f32x4 s_acc[4];
#pragma unroll
        for (int mt = 0; mt < 4; ++mt) {
            f32x4 a = {0.f, 0.f, 0.f, 0.f};
#pragma unroll
            for (int kk = 0; kk < 4; ++kk) {
                short8 kf = *(const short8*)&KsB[(mt * 16 + c) * 128 +
                                                 (((kk * 4 + quad) ^ c) << 3)];
                a = __builtin_amdgcn_mfma_f32_16x16x32_bf16(kf, qf[kk], a, 0, 0, 0);
            }
            s_acc[mt] = a;
        }

#pragma unroll
        for (int mt = 0; mt < 4; ++mt) {
            float pv[4];
#pragma unroll
            for (int reg = 0; reg < 4; ++reg) {
                float g2 = cb * cOff[mt][reg] - sb * sOff[mt][reg];
                float arg = fmaf(s_acc[mt][reg], g2, -SM_M * L2E);
                if (diag && (mt * 16 + quad * 4 + reg) > t_l) arg = -1e30f;
                pv[reg] = exp2f(arg);
            }
            lsum += (pv[0] + pv[1]) + (pv[2] + pv[3]);
            uint2 pk = {pack2bf_fast(pv[0], pv[1]), pack2bf_fast(pv[2], pv[3])};
            int slot = ((mt * 2 + (quad >> 1)) ^ (c & 7));
            *(uint2*)&Ps[wave][c * 64 + slot * 8 + (quad & 1) * 4] = pk;
        }

        float ncb = cb * cD - sb * sD;         // advance one 64-tile
        sb = sb * cD + cb * sD;
        cb = ncb;
    };

    auto do_pv = [&](int buf) {
        const short* VtB = &Vt[buf][0];
        short8 pf[2];
#pragma unroll
        for (int kk = 0; kk < 2; ++kk)
            pf[kk] = *(const short8*)&Ps[wave][c * 64 +
                         (((kk * 4 + quad) ^ (c & 7)) << 3)];
#pragma unroll
        for (int nt = 0; nt < 4; ++nt)
#pragma unroll
            for (int kk = 0; kk < 2; ++kk) {
                short8 vf = *(const short8*)&VtB[(nt * 16 + c) * 64 +
                             (((kk * 4 + quad) ^ (c & 7)) << 3)];
                oacc[nt] = __builtin_amdgcn_mfma_f32_16x16x32_bf16(
                    pf[kk], vf, oacc[nt], 0, 0, 0);
            }
    };

    auto write_out = [&]() {
        float l = lsum;
        l += __shfl_xor(l, 16);
        l += __shfl_xor(l, 32);
        float il = 1.f / l;
        float ilr[4];
#pragma unroll
        for (int reg = 0; reg < 4; ++reg)
            ilr[reg] = __shfl(il, quad * 4 + reg);
#pragma unroll
        for (int reg = 0; reg < 4; ++reg) {
            int t_o = q0 + gw * 16 + quad * 4 + reg;
#pragma unroll
            for (int nt = 0; nt < 4; ++nt)
                att[(size_t)(b * Tc + t_o) * Cc + h * Dc + nt * 16 + c] =
                    f2bf(oacc[nt][reg] * ilr[reg]);
        }
    };

    // ---- phase 1: jt = 0..p, shared staging, prefetch jt+1 (v6 verbatim)
    stageK_all(0, 0); stageV_all(0, 0);
    for (int jt = 0; jt <= p; ++jt) {
        __syncthreads();
        stageK_all(jt + 1, (jt + 1) & 1);      // jt==p stages B's first ph2 tile
        stageV_all(jt + 1, (jt + 1) & 1);
        do_s(jt, jt & 1);
        do_pv(jt & 1);
    }
    const int slotB = (p + 1) & 1, slotA = slotB ^ 1;

    // ---- transition
    __syncthreads();                           // tile p+1 landed; phase-1 reads done
    if (p < 15) PF_LOAD(tx ? (p + 2) : 17);    // first ph2 tile -> regs; latency
                                               // hides under transition work
    if (tx == 0) {
        write_out();                           // qA complete
#pragma unroll
        for (int nt = 0; nt < 4; ++nt)
            oacc[nt] = (f32x4){0.f, 0.f, 0.f, 0.f};
        lsum = 0.f;
        qcur = qB; q0 = qB * 64;
        const short* qp = q2b + (size_t)(q0 + t_l) * 128;
#pragma unroll
        for (int i = 0; i < 4; ++i)
            qf[i] = *(const short8*)(qp + i * 32 + quad * 8);
        float a = th * 0.125f * (1088.f - (float)(q0 + t_l));   // base @ jt=17
        __sincosf(a, &sb, &cb);
    } else {
        do_s(p + 1, slotB);                    // diag here only when p==15
        do_pv(slotB);
    }

    // ---- phase 2: 15-p iterations, both groups busy, T14 reg prefetch.
    // Per iter: barrier (WAR: prior reads of slot done) -> PF_WRITE (compiler
    // waits the loads; they landed under the prior iteration's compute) ->
    // barrier (writes visible) -> PF_LOAD(jt+1) -> compute jt.
    for (int i = 0; i <= 14 - p; ++i) {
        const int jt = tx ? (p + 2 + i) : (17 + i);
        const int sl = tx ? slotB : slotA;
        __syncthreads();
        PF_WRITE(sl);
        __syncthreads();
        if (i < 14 - p) PF_LOAD(jt + 1);
        do_s(jt, sl);
        do_pv(sl);
    }
#undef PF_LOAD
#undef PF_WRITE

    // ---- combine qB partials: A -> LDS (reuse Ks), B adds + writes
    __syncthreads();
    float* Cmb = (float*)&Ks[0][0];            // 256 x 20 f32 = 20 KB of 32 KB
    if (tx == 0) {
        float* pp = Cmb + (size_t)(gw * 64 + lane) * 20;
#pragma unroll
        for (int nt = 0; nt < 4; ++nt) *(f32x4*)(pp + nt * 4) = oacc[nt];
        pp[16] = lsum;
    }
    __syncthreads();
    if (tx == 1) {
        const float* pp = Cmb + (size_t)(gw * 64 + lane) * 20;
#pragma unroll
        for (int nt = 0; nt < 4; ++nt)
            oacc[nt] += *(const f32x4*)(pp + nt * 4);
        lsum += pp[16];
        write_out();
    }
}

// ---------------------------------------------------------------------------
extern "C" void kernel_launch(void* const* d_in, const int* in_sizes, int n_in,
                              void* d_out, int out_size, void* d_ws, size_t ws_size,
                              hipStream_t stream)
{
    const float* x     = (const float*)d_in[0];
    const float* Wq    = (const float*)d_in[1];
    const float* Wk    = (const float*)d_in[2];
    const float* Wv    = (const float*)d_in[3];
    const float* Wo    = (const float*)d_in[4];
    const float* theta = (const float*)d_in[5];
    float* out = (float*)d_out;

    const int M = Bc * Tc;                 // 4096
    char* ws = (char*)d_ws;
    const size_t MB = 1 << 20;
    short* xb   = (short*)(ws);             // [0,8)   x bf16
    short* Bqk  = (short*)(ws + 8 * MB);    // [8,16)  permuted [Wq'|Wk']^T bf16
    short* Wvt  = (short*)(ws + 16 * MB);   // [16,18)
    short* Wot  = (short*)(ws + 18 * MB);   // [18,20)
    short* v2t  = (short*)(ws + 28 * MB);   // [28,36) bf16 (B,H,D,T)
    short* attb = (short*)(ws + 36 * MB);   // [36,44)
    short* q2   = (short*)(ws + 44 * MB);   // [44,60) bf16 (B,H,T,128)
    short* k2   = (short*)d_out;            // 16 MB   bf16 (B,H,T,128) until final gemm

    xconv<<<(size_t)M * Cc / 1024, 256, 0, stream>>>(x, xb);
    wtrans_qk<<<dim3(2048 / 64, Cc / 64, 2), 256, 0, stream>>>(Wq, Wk, Bqk);
    wtrans2<<<dim3(Cc / 64, Cc / 64, 2), 256, 0, stream>>>(Wv, Wo, Wvt);

    // fused QK projection + moire transform (256^2 8-phase, writes q2, k2)
    gemm256_qk<<<dim3(4096 / 256, M / 256), 512, 0, stream>>>(xb, Bqk, q2, k2);
    // fused V projection + head-transpose (writes v2t directly)
    gemm_v2t<<<dim3(Cc / 128, M / 128), 512, 0, stream>>>(xb, Wvt, v2t);

    moire_attn10<<<dim3(16, Hc, Bc), 512, 0, stream>>>(q2, k2, v2t, theta, attb);

    gemm_bt_mfma<0><<<dim3(Cc / 128, M / 128), 512, 0, stream>>>(
        attb, Wot, out, nullptr, M, Cc, Cc);
}

// Round 11
// 227.223 us; speedup vs baseline: 1.8070x; 1.2951x over previous
//
#include <hip/hip_runtime.h>
#include <hip/hip_bf16.h>
#include <math.h>

// Problem constants
#define Bc 2
#define Tc 2048
#define Cc 1024
#define Hc 16
#define Dc 64
// SCALE = 1/8, GAMMA = 8

typedef __attribute__((ext_vector_type(8))) short short8;   // 8 bf16 (4 VGPRs)
typedef __attribute__((ext_vector_type(4))) float f32x4;    // MFMA C/D frag

#define L2E 1.44269504088896f
#define SM_M 20.0f   // fixed softmax shift; |scores| << 20 (std ~0.3)

__device__ __forceinline__ short f2bf(float x) {
    unsigned u = __float_as_uint(x);
    u += 0x7fff + ((u >> 16) & 1);      // RNE
    return (short)(u >> 16);
}
// pack two non-negative floats to bf16 pair (round-half-up) in 3 VALU ops
__device__ __forceinline__ unsigned pack2bf_fast(float a, float b) {
    unsigned ua = __float_as_uint(a) + 0x8000u;
    unsigned ub = __float_as_uint(b) + 0x8000u;
    return __builtin_amdgcn_perm(ub, ua, 0x07060302);  // (ua>>16)|(ub&0xffff0000)
}
// fast softplus: 2 HW transcendentals, ~1e-6 rel err (invisible at bf16)
__device__ __forceinline__ float softplus_fast(float a) {
    return fmaxf(a, 0.f) + __logf(1.f + __expf(-fabsf(a)));
}

// ---------------------------------------------------------------------------
// 256x256 8-phase bf16 GEMM with fused moire-QK epilogue (m201 template).
// R6: + XCD-aware bijective block swizzle (T1).  (unchanged from R8-verified)
// ---------------------------------------------------------------------------
#define RDA(BUF, MH) do {                                                      \
    const short* Ah_ = &Al[BUF][MH][0];                                        \
    _Pragma("unroll") for (int mt_ = 0; mt_ < 4; ++mt_) {                      \
        af[mt_][0] = *(const short8*)&Ah_[(wm*64 + mt_*16 + c)*64 + rsw0];     \
        af[mt_][1] = *(const short8*)&Ah_[(wm*64 + mt_*16 + c)*64 + rsw1];     \
    } } while (0)

#define RDB(BUF, NH) do {                                                      \
    const short* Bh_ = &Bl[BUF][NH][0];                                        \
    _Pragma("unroll") for (int nf_ = 0; nf_ < 2; ++nf_) {                      \
        bfr[NH][nf_][0] = *(const short8*)&Bh_[(wn*32 + nf_*16 + c)*64 + rsw0];\
        bfr[NH][nf_][1] = *(const short8*)&Bh_[(wn*32 + nf_*16 + c)*64 + rsw1];\
    } } while (0)

#define MMQ(MH, NH) do {                                                       \
    _Pragma("unroll") for (int mt_ = 0; mt_ < 4; ++mt_)                        \
    _Pragma("unroll") for (int nf_ = 0; nf_ < 2; ++nf_) {                      \
        acc[MH][NH][mt_][nf_] = __builtin_amdgcn_mfma_f32_16x16x32_bf16(       \
            af[mt_][0], bfr[NH][nf_][0], acc[MH][NH][mt_][nf_], 0, 0, 0);      \
        acc[MH][NH][mt_][nf_] = __builtin_amdgcn_mfma_f32_16x16x32_bf16(       \
            af[mt_][1], bfr[NH][nf_][1], acc[MH][NH][mt_][nf_], 0, 0, 0);      \
    } } while (0)

#define BARw asm volatile("s_barrier" ::: "memory")
#define VMW6 asm volatile("s_waitcnt vmcnt(6)" ::: "memory")
#define VMW0 asm volatile("s_waitcnt vmcnt(0)" ::: "memory")
#define PRIO1 __builtin_amdgcn_s_setprio(1)
#define PRIO0 __builtin_amdgcn_s_setprio(0)

__global__ __launch_bounds__(512, 2) void gemm256_qk(
    const short* __restrict__ A, const short* __restrict__ Bt,
    short* __restrict__ q2, short* __restrict__ k2)
{
    __shared__ __attribute__((aligned(16))) short Al[2][2][128 * 64];  // 64 KB
    __shared__ __attribute__((aligned(16))) short Bl[2][2][128 * 64];  // 64 KB

    const int tid = threadIdx.x;
    const int wave = tid >> 6, lane = tid & 63;
    const int quad = lane >> 4, c = lane & 15;
    const int wm = wave >> 2, wn = wave & 3;          // 2M x 4N waves
    // XCD-chunked bijective swizzle: f%8 = XCD (round-robin dispatch);
    // XCD k owns w in [32k,32k+32) = 2 full grid rows -> A-panel L2 reuse.
    const int f = blockIdx.x + 16 * blockIdx.y;       // 0..255
    const int w = (f & 7) * 32 + (f >> 3);
    const int bx = w & 15, by = w >> 4;
    const int m0 = by * 256, n0 = bx * 256;

    // swizzled ds_read byte-slot (shorts): (ks*64 + quad*16) ^ ((c&7)<<4)
    const int rsw0 = ((quad * 16) ^ ((c & 7) << 4)) >> 1;
    const int rsw1 = ((64 + quad * 16) ^ ((c & 7) << 4)) >> 1;

    f32x4 acc[2][2][4][2];
#pragma unroll
    for (int a0 = 0; a0 < 2; ++a0)
#pragma unroll
        for (int a1 = 0; a1 < 2; ++a1)
#pragma unroll
            for (int a2 = 0; a2 < 4; ++a2)
#pragma unroll
                for (int a3 = 0; a3 < 2; ++a3)
                    acc[a0][a1][a2][a3] = (f32x4){0.f, 0.f, 0.f, 0.f};

    short8 af[4][2];        // A-frags: 4 m-frags x 2 k-steps (32 VGPR)
    short8 bfr[2][2][2];    // B-frags: [nh][nf][ks] both halves kept (32 VGPR)

    auto stA = [&](int kt, int hh) {
        short* dstb = &Al[kt & 1][hh][0];
#pragma unroll
        for (int j = 0; j < 2; ++j) {
            int ch = j * 512 + tid;
            int row = ch >> 3;
            int os = ((((ch & 7) << 4) ^ ((row & 7) << 4)) >> 1);
            const short* src = A + (size_t)(m0 + hh * 128 + row) * 1024 + kt * 64 + os;
            __builtin_amdgcn_global_load_lds(
                (const __attribute__((address_space(1))) void*)src,
                (__attribute__((address_space(3))) void*)(dstb + (j * 512 + wave * 64) * 8),
                16, 0, 0);
        }
    };
    auto stB = [&](int kt, int hh) {
        short* dstb = &Bl[kt & 1][hh][0];
#pragma unroll
        for (int j = 0; j < 2; ++j) {
            int ch = j * 512 + tid;
            int row = ch >> 3;
            int os = ((((ch & 7) << 4) ^ ((row & 7) << 4)) >> 1);
            const short* src = Bt + (size_t)(n0 + hh * 128 + row) * 1024 + kt * 64 + os;
            __builtin_amdgcn_global_load_lds(
                (const __attribute__((address_space(1))) void*)src,
                (__attribute__((address_space(3))) void*)(dstb + (j * 512 + wave * 64) * 8),
                16, 0, 0);
        }
    };

    // prologue: tile0 fully + tile1 {Bh0, Ah0, Bh1}; Ah1(1) comes at p1 of i=0.
    stB(0, 0); stA(0, 0); stB(0, 1); stA(0, 1); stB(1, 0); stA(1, 0); stB(1, 1);
    VMW6;          // oldest 8 loads (= all of tile 0) landed
    BARw;

    // K = 1024 -> 16 K-tiles -> 8 iterations of 2 tiles (buf0 = even tile).
    for (int i = 0; i < 8; ++i) {
        const int e = 2 * i;
        const bool more = (i < 7);
        // ---- group e (buf 0) ----
        RDA(0, 0); RDB(0, 0);                 // p1: 12 ds_reads
        stA(e + 1, 1);                        //     stage Ah1(odd tile)
        BARw; PRIO1; MMQ(0, 0); PRIO0; BARw;
        RDB(0, 1);                            // p2: 4 ds_reads (A kept)
        if (more) stB(e + 2, 0);
        BARw; PRIO1; MMQ(0, 1); PRIO0; BARw;
        RDA(0, 1);                            // p3: 8 ds_reads (B0 kept)
        if (more) stA(e + 2, 0);
        BARw; PRIO1; MMQ(1, 0); PRIO0; BARw;
        if (more) stB(e + 2, 1);              // p4: no ds_reads (A,B1 kept)
        BARw; PRIO1; MMQ(1, 1); PRIO0;
        if (more) { VMW6; } else { VMW0; }
        BARw;
        // ---- group o (buf 1) ----
        RDA(1, 0); RDB(1, 0);                 // p5
        if (more) stA(e + 2, 1);
        BARw; PRIO1; MMQ(0, 0); PRIO0; BARw;
        RDB(1, 1);                            // p6
        if (more) stB(e + 3, 0);
        BARw; PRIO1; MMQ(0, 1); PRIO0; BARw;
        RDA(1, 1);                            // p7
        if (more) stA(e + 3, 0);
        BARw; PRIO1; MMQ(1, 0); PRIO0; BARw;
        if (more) stB(e + 3, 1);              // p8
        BARw; PRIO1; MMQ(1, 1); PRIO0;
        if (more) { VMW6; } else { VMW0; }
        BARw;
    }

    // moire epilogue: cols of this lane: n = n0 + nh*128 + wn*32 + nf*16 + c
    const int d = wn * 16 + c;
#pragma unroll
    for (int mh = 0; mh < 2; ++mh) {
#pragma unroll
        for (int nh = 0; nh < 2; ++nh) {
            const int g = 2 * bx + nh;
            const int isK = g >> 4;
            const int hh = g & 15;
            const float scl = isK ? 1.f : 0.125f;
            short* dst = isK ? k2 : q2;       // (B,H,T,128)
#pragma unroll
            for (int mt = 0; mt < 4; ++mt) {
#pragma unroll
                for (int reg = 0; reg < 4; ++reg) {
                    int m = m0 + mh * 128 + wm * 64 + mt * 16 + quad * 4 + reg;
                    int bb = m >> 11, tt = m & (Tc - 1);
                    size_t base = (((size_t)bb * Hc + hh) * Tc + tt) * 128;
                    float amp = acc[mh][nh][mt][0][reg];
                    float ph  = acc[mh][nh][mt][1][reg];
                    float sp = softplus_fast(amp) * scl;
                    float sn, cs;
                    __sincosf(ph, &sn, &cs);
                    dst[base + d]      = f2bf(sp * cs);
                    dst[base + d + 64] = f2bf(sp * sn);
                }
            }
        }
    }
}

// ---------------------------------------------------------------------------
// bf16 MFMA GEMM, 128x64-tile variant (R11): grid doubles to 512 blocks =
// 2 INDEPENDENT blocks/CU. R5 lesson: 8 waves in ONE block are lockstep at
// the block barrier -- m114's latency overlap needs independent blocks, and
// grid=256 pinned us at 1 block/CU. 256 threads, 2M x 2N waves, per-wave
// 64x32 output (acc[4][2]). LDS: As 8KB + Bs 4KB (m97-proven layout).
// Accumulation order per output element unchanged -> bit-identical.
// ---------------------------------------------------------------------------
__global__ __launch_bounds__(256) void gemm_bt64(
    const short* __restrict__ A, const short* __restrict__ Bt,
    float* __restrict__ Cf, int M, int N, int K)
{
    __shared__ __attribute__((aligned(16))) short As[128 * 32];
    __shared__ __attribute__((aligned(16))) short Bs[64 * 32];

    const int tid = threadIdx.x;
    const int lane = tid & 63;
    const int wave = tid >> 6;
    const int quad = lane >> 4, c = lane & 15;
    const int wm = wave >> 1, wn = wave & 1;          // 2M x 2N waves
    const int m0 = blockIdx.y * 128, n0 = blockIdx.x * 64;

    // A: 512 chunks (16B), 2/thread; B: 256 chunks, 1/thread
    const int rA0 = tid >> 2,        cA0 = (tid & 3) * 8;
    const int rA1 = (256 + tid) >> 2, cA1 = ((256 + tid) & 3) * 8;
    const int rB = tid >> 2,         cB = (tid & 3) * 8;
    const short* Ag0 = A + (size_t)(m0 + rA0) * K + cA0;
    const short* Ag1 = A + (size_t)(m0 + rA1) * K + cA1;
    const short* Bg = Bt + (size_t)(n0 + rB) * K + cB;
    short* AsW0 = As + tid * 8;
    short* AsW1 = As + (256 + tid) * 8;
    short* BsW = Bs + tid * 8;

    f32x4 acc[4][2];
#pragma unroll
    for (int i = 0; i < 4; ++i)
#pragma unroll
        for (int j = 0; j < 2; ++j)
            acc[i][j] = (f32x4){0.f, 0.f, 0.f, 0.f};

    for (int k0 = 0; k0 < K; k0 += 32) {
        __syncthreads();
        __builtin_amdgcn_global_load_lds(
            (const __attribute__((address_space(1))) void*)(Ag0 + k0),
            (__attribute__((address_space(3))) void*)AsW0, 16, 0, 0);
        __builtin_amdgcn_global_load_lds(
            (const __attribute__((address_space(1))) void*)(Ag1 + k0),
            (__attribute__((address_space(3))) void*)AsW1, 16, 0, 0);
        __builtin_amdgcn_global_load_lds(
            (const __attribute__((address_space(1))) void*)(Bg + k0),
            (__attribute__((address_space(3))) void*)BsW, 16, 0, 0);
        __syncthreads();

        short8 af[4], bf[2];
#pragma unroll
        for (int mt = 0; mt < 4; ++mt)
            af[mt] = *(const short8*)&As[(wm * 64 + mt * 16 + c) * 32 + quad * 8];
#pragma unroll
        for (int nt = 0; nt < 2; ++nt)
            bf[nt] = *(const short8*)&Bs[(wn * 32 + nt * 16 + c) * 32 + quad * 8];
#pragma unroll
        for (int mt = 0; mt < 4; ++mt)
#pragma unroll
            for (int nt = 0; nt < 2; ++nt)
                acc[mt][nt] = __builtin_amdgcn_mfma_f32_16x16x32_bf16(
                    af[mt], bf[nt], acc[mt][nt], 0, 0, 0);
    }

#pragma unroll
    for (int mt = 0; mt < 4; ++mt) {
#pragma unroll
        for (int reg = 0; reg < 4; ++reg) {
            size_t row = m0 + wm * 64 + mt * 16 + quad * 4 + reg;
#pragma unroll
            for (int nt = 0; nt < 2; ++nt) {
                size_t col = n0 + wn * 32 + nt * 16 + c;
                Cf[row * N + col] = acc[mt][nt][reg];
            }
        }
    }
}

// ---------------------------------------------------------------------------
// V projection fused with head-transpose, 128x64-tile variant (R11): same
// rationale as gemm_bt64 (2 independent blocks/CU). Output tile [t=128][n=64]
// transposed through LDS (pitch 136, proven layout) then 16B-run stores.
// ---------------------------------------------------------------------------
__global__ __launch_bounds__(256) void gemm_v2t64(
    const short* __restrict__ A, const short* __restrict__ Bt,
    short* __restrict__ v2t)
{
    __shared__ __attribute__((aligned(16))) short As[128 * 32];
    __shared__ __attribute__((aligned(16))) short Bs[64 * 32];
    __shared__ __attribute__((aligned(16))) short tile[64 * 136];  // [n][t]

    const int K = Cc;
    const int tid = threadIdx.x;
    const int lane = tid & 63;
    const int wave = tid >> 6;
    const int quad = lane >> 4, c = lane & 15;
    const int wm = wave >> 1, wn = wave & 1;          // 2M x 2N waves
    const int m0 = blockIdx.y * 128, n0 = blockIdx.x * 64;

    const int rA0 = tid >> 2,        cA0 = (tid & 3) * 8;
    const int rA1 = (256 + tid) >> 2, cA1 = ((256 + tid) & 3) * 8;
    const int rB = tid >> 2,         cB = (tid & 3) * 8;
    const short* Ag0 = A + (size_t)(m0 + rA0) * K + cA0;
    const short* Ag1 = A + (size_t)(m0 + rA1) * K + cA1;
    const short* Bg = Bt + (size_t)(n0 + rB) * K + cB;
    short* AsW0 = As + tid * 8;
    short* AsW1 = As + (256 + tid) * 8;
    short* BsW = Bs + tid * 8;

    f32x4 acc[4][2];
#pragma unroll
    for (int i = 0; i < 4; ++i)
#pragma unroll
        for (int j = 0; j < 2; ++j)
            acc[i][j] = (f32x4){0.f, 0.f, 0.f, 0.f};

    for (int k0 = 0; k0 < K; k0 += 32) {
        __syncthreads();
        __builtin_amdgcn_global_load_lds(
            (const __attribute__((address_space(1))) void*)(Ag0 + k0),
            (__attribute__((address_space(3))) void*)AsW0, 16, 0, 0);
        __builtin_amdgcn_global_load_lds(
            (const __attribute__((address_space(1))) void*)(Ag1 + k0),
            (__attribute__((address_space(3))) void*)AsW1, 16, 0, 0);
        __builtin_amdgcn_global_load_lds(
            (const __attribute__((address_space(1))) void*)(Bg + k0),
            (__attribute__((address_space(3))) void*)BsW, 16, 0, 0);
        __syncthreads();

        short8 af[4], bf[2];
#pragma unroll
        for (int mt = 0; mt < 4; ++mt)
            af[mt] = *(const short8*)&As[(wm * 64 + mt * 16 + c) * 32 + quad * 8];
#pragma unroll
        for (int nt = 0; nt < 2; ++nt)
            bf[nt] = *(const short8*)&Bs[(wn * 32 + nt * 16 + c) * 32 + quad * 8];
#pragma unroll
        for (int mt = 0; mt < 4; ++mt)
#pragma unroll
            for (int nt = 0; nt < 2; ++nt)
                acc[mt][nt] = __builtin_amdgcn_mfma_f32_16x16x32_bf16(
                    af[mt], bf[nt], acc[mt][nt], 0, 0, 0);
    }

    // epilogue: stash transposed into LDS [n][t]
#pragma unroll
    for (int mt = 0; mt < 4; ++mt)
#pragma unroll
        for (int reg = 0; reg < 4; ++reg) {
            int tl = wm * 64 + mt * 16 + quad * 4 + reg;
#pragma unroll
            for (int nt = 0; nt < 2; ++nt)
                tile[(wn * 32 + nt * 16 + c) * 136 + tl] = f2bf(acc[mt][nt][reg]);
        }
    __syncthreads();

    const int b = m0 >> 11, tl0 = m0 & (Tc - 1);
#pragma unroll
    for (int i = 0; i < 4; ++i) {
        int e = i * 256 + tid;                // 1024 short8 chunks
        int n = e >> 4;
        int t8 = (e & 15) * 8;
        int ng = n0 + n, h = ng >> 6, d = ng & 63;
        *(short8*)&v2t[(((size_t)b * Hc + h) * Dc + d) * Tc + tl0 + t8] =
            *(const short8*)&tile[n * 136 + t8];
    }
}

// ---------------------------------------------------------------------------
__global__ __launch_bounds__(256) void xconv(const float* __restrict__ x,
                                             short* __restrict__ xb)
{
    int idx = blockIdx.x * 256 + threadIdx.x;
    float4 v = *(const float4*)&x[(size_t)idx * 4];
    short4 o = {f2bf(v.x), f2bf(v.y), f2bf(v.z), f2bf(v.w)};
    short4* dst = (short4*)&xb[(size_t)idx * 4];
    *dst = o;
}

// ---------------------------------------------------------------------------
// Wq|Wk transpose-convert with the gemm256_qk row permutation.
// ---------------------------------------------------------------------------
__global__ __launch_bounds__(256) void wtrans_qk(const float* __restrict__ Wq,
                                                 const float* __restrict__ Wk,
                                                 short* __restrict__ Bt)
{
    __shared__ short tile[64][80];
    const int n0 = blockIdx.x * 64, k0 = blockIdx.y * 64;
    const int half = blockIdx.z;
    const float* W = half ? Wk : Wq;
    const int tid = threadIdx.x;
#pragma unroll
    for (int i = 0; i < 4; ++i) {
        int e = i * 256 + tid;
        int k = e >> 4, n4 = (e & 15) * 4;
        float4 v = *(const float4*)&W[(size_t)(k0 + k) * 2048 + n0 + n4];
        tile[k][n4]     = f2bf(v.x);
        tile[k][n4 + 1] = f2bf(v.y);
        tile[k][n4 + 2] = f2bf(v.z);
        tile[k][n4 + 3] = f2bf(v.w);
    }
    __syncthreads();
#pragma unroll
    for (int i = 0; i < 16; ++i) {
        int e = i * 256 + tid;
        int n = e >> 6, k = e & 63;
        int ng = n0 + n;
        int sub = ng >> 10, hh = (ng >> 6) & 15, dd = ng & 63;
        int r = (half * 16 + hh) * 128 + (dd >> 4) * 32 + sub * 16 + (dd & 15);
        Bt[(size_t)r * Cc + k0 + k] = tile[k][n];
    }
}

// ---------------------------------------------------------------------------
__global__ __launch_bounds__(256) void wtrans2(const float* __restrict__ Wv,
                                               const float* __restrict__ Wo,
                                               short* __restrict__ WtBase)
{
    __shared__ short tile[64][80];
    const int n0 = blockIdx.x * 64, k0 = blockIdx.y * 64;
    const float* W = blockIdx.z ? Wo : Wv;
    short* Wt = WtBase + (size_t)blockIdx.z * Cc * Cc;
    const int tid = threadIdx.x;
#pragma unroll
    for (int i = 0; i < 4; ++i) {
        int e = i * 256 + tid;
        int k = e >> 4, n4 = (e & 15) * 4;
        float4 v = *(const float4*)&W[(size_t)(k0 + k) * Cc + n0 + n4];
        tile[k][n4]     = f2bf(v.x);
        tile[k][n4 + 1] = f2bf(v.y);
        tile[k][n4 + 2] = f2bf(v.z);
        tile[k][n4 + 3] = f2bf(v.w);
    }
    __syncthreads();
#pragma unroll
    for (int i = 0; i < 16; ++i) {
        int e = i * 256 + tid;
        int n = e >> 6, k = e & 63;
        Wt[(size_t)(n0 + n) * Cc + k0 + k] = tile[k][n];
    }
}

// ---------------------------------------------------------------------------
// MFMA flash attention v8 + XCD swizzle -- EXACT R8-verified version
// (61.4 us, FETCH 22 MB). T14 prefetch abandoned: two implementations
// (R9 lambda-arrays, R10 named scalars+macros) both scratch-spilled
// (WRITE_SIZE 237/102 MB, VGPR pinned at 64) -- compiler-blocked.
// ---------------------------------------------------------------------------
__global__ __launch_bounds__(512, 4) void moire_attn8(
    const short* __restrict__ q2, const short* __restrict__ k2,
    const short* __restrict__ v2t, const float* __restrict__ theta,
    short* __restrict__ att)
{
    __shared__ __attribute__((aligned(16))) short Ks[2][64 * 128];  // 32 KB
    __shared__ __attribute__((aligned(16))) short Vt[2][64 * 64];   // 16 KB
    __shared__ __attribute__((aligned(16))) short Ps[8][16 * 64];   // 16 KB

    const int tid = threadIdx.x;
    const int wave = tid >> 6, lane = tid & 63;
    const int quad = lane >> 4, c = lane & 15;
    const int tx = wave >> 2, gw = wave & 3;
    // XCD-chunked bijective swizzle (T1): f%8 = XCD; XCD k gets 4 (h,b) pairs.
    const int f = blockIdx.x + 16 * (blockIdx.y + 16 * blockIdx.z);  // 0..511
    const int w = (f & 7) * 64 + (f >> 3);
    const int p = w & 15;
    const int hb = w >> 4;                    // 0..31
    const int h = hb & 15, b = hb >> 4;
    const int qB = 31 - p;
    const float th = theta[h];

    const short* k2b = k2 + (size_t)(b * Hc + h) * Tc * 128;
    const short* v2b = v2t + (size_t)(b * Hc + h) * Dc * Tc;
    const short* q2b = q2 + (size_t)(b * Hc + h) * Tc * 128;

    // current target q-tile state (group A switches at the transition)
    int qcur = tx ? qB : p;
    int q0 = qcur * 64;
    const int t_l = gw * 16 + c;

    // Q B-frags (n = t): row q0 + t_l, 4 K-chunks of 32
    short8 qf[4];
    {
        const short* qp = q2b + (size_t)(q0 + t_l) * 128;
#pragma unroll
        for (int i = 0; i < 4; ++i)
            qf[i] = *(const short8*)(qp + i * 32 + quad * 8);
    }

    // gate*L2E = cb*cOff - sb*sOff; (cb,sb) = (cos,sin) of th/8*(jt*64 - t_g)
    float x0 = th * 0.125f * (float)(q0 + t_l);
    float cb = __cosf(x0), sb = -__sinf(x0);
    float cOff[4][4], sOff[4][4];
#pragma unroll
    for (int mt = 0; mt < 4; ++mt)
#pragma unroll
        for (int reg = 0; reg < 4; ++reg) {
            float a = th * 0.125f * (float)(mt * 16 + quad * 4 + reg);
            cOff[mt][reg] = __cosf(a) * L2E;
            sOff[mt][reg] = __sinf(a) * L2E;
        }
    const float cD = __cosf(8.f * th), sD = __sinf(8.f * th);  // 64-step rot

    f32x4 oacc[4];
    float lsum = 0.f;
#pragma unroll
    for (int nt = 0; nt < 4; ++nt)
        oacc[nt] = (f32x4){0.f, 0.f, 0.f, 0.f};

    // ---- staging: all-thread (phase 1) and per-group (phase 2) variants.
    // LDS image identical in both (chunk -> (row, swizzled col) mapping).
    auto stageK_all = [&](int jts, int buf) {
        short* dst = &Ks[buf][0];
        const int s0 = jts * 64;
#pragma unroll
        for (int i = 0; i < 2; ++i) {          // 1024 16B chunks, 2/thread
            int ch = i * 512 + tid;
            int row = ch >> 4, j = ch & 15;
            const short* src = k2b + (size_t)(s0 + row) * 128 + ((j ^ (row & 15)) << 3);
            __builtin_amdgcn_global_load_lds(
                (const __attribute__((address_space(1))) void*)src,
                (__attribute__((address_space(3))) void*)(dst + (i * 512 + wave * 64) * 8),
                16, 0, 0);
        }
    };
    auto stageV_all = [&](int jts, int buf) {
        short* dst = &Vt[buf][0];
        const int s0 = jts * 64;
        int row = tid >> 3, j = tid & 7;       // 512 16B chunks, 1/thread
        const short* src = v2b + (size_t)row * Tc + s0 + ((j ^ (row & 7)) << 3);
        __builtin_amdgcn_global_load_lds(
            (const __attribute__((address_space(1))) void*)src,
            (__attribute__((address_space(3))) void*)(dst + (wave * 64) * 8),
            16, 0, 0);
    };
    auto stage_grp = [&](int jts, int buf) {   // 256 threads of own group
        const int s0 = jts * 64;
        const int ltid = tid & 255;            // = gw*64 + lane
        short* dk = &Ks[buf][0];
#pragma unroll
        for (int jj = 0; jj < 4; ++jj) {       // K: 1024 chunks, 4/thread
            int ch = jj * 256 + ltid;
            int row = ch >> 4, j = ch & 15;
            const short* src = k2b + (size_t)(s0 + row) * 128 + ((j ^ (row & 15)) << 3);
            __builtin_amdgcn_global_load_lds(
                (const __attribute__((address_space(1))) void*)src,
                (__attribute__((address_space(3))) void*)(dk + (jj * 256 + gw * 64) * 8),
                16, 0, 0);
        }
        short* dv = &Vt[buf][0];
#pragma unroll
        for (int jj = 0; jj < 2; ++jj) {       // V: 512 chunks, 2/thread
            int ch = jj * 256 + ltid;
            int row = ch >> 3, j = ch & 7;
            const short* src = v2b + (size_t)row * Tc + s0 + ((j ^ (row & 7)) << 3);
            __builtin_amdgcn_global_load_lds(
                (const __attribute__((address_space(1))) void*)src,
                (__attribute__((address_space(3))) void*)(dv + (jj * 256 + gw * 64) * 8),
                16, 0, 0);
        }
    };

    // S^T + softmax + Ps write for tile jt from slot buf; rotates base angle.
    auto do_s = [&](int jt, int buf) {
        const short* KsB = &Ks[buf][0];
        const bool diag = (jt == qcur);

        f32x4 s_acc[4];
#pragma unroll
        for (int mt = 0; mt < 4; ++mt) {
            f32x4 a = {0.f, 0.f, 0.f, 0.f};
#pragma unroll
            for (int kk = 0; kk < 4; ++kk) {
                short8 kf = *(const short8*)&KsB[(mt * 16 + c) * 128 +
                                                 (((kk * 4 + quad) ^ c) << 3)];
                a = __builtin_amdgcn_mfma_f32_16x16x32_bf16(kf, qf[kk], a, 0, 0, 0);
            }
            s_acc[mt] = a;
        }

#pragma unroll
        for (int mt = 0; mt < 4; ++mt) {
            float pv[4];
#pragma unroll
            for (int reg = 0; reg < 4; ++reg) {
                float g2 = cb * cOff[mt][reg] - sb * sOff[mt][reg];
                float arg = fmaf(s_acc[mt][reg], g2, -SM_M * L2E);
                if (diag && (mt * 16 + quad * 4 + reg) > t_l) arg = -1e30f;
                pv[reg] = exp2f(arg);
            }
            lsum += (pv[0] + pv[1]) + (pv[2] + pv[3]);
            uint2 pk = {pack2bf_fast(pv[0], pv[1]), pack2bf_fast(pv[2], pv[3])};
            int slot = ((mt * 2 + (quad >> 1)) ^ (c & 7));
            *(uint2*)&Ps[wave][c * 64 + slot * 8 + (quad & 1) * 4] = pk;
        }

        float ncb = cb * cD - sb * sD;         // advance one 64-tile
        sb = sb * cD + cb * sD;
        cb = ncb;
    };

    auto do_pv = [&](int buf) {
        const short* VtB = &Vt[buf][0];
        short8 pf[2];
#pragma unroll
        for (int kk = 0; kk < 2; ++kk)
            pf[kk] = *(const short8*)&Ps[wave][c * 64 +
                         (((kk * 4 + quad) ^ (c & 7)) << 3)];
#pragma unroll
        for (int nt = 0; nt < 4; ++nt)
#pragma unroll
            for (int kk = 0; kk < 2; ++kk) {
                short8 vf = *(const short8*)&VtB[(nt * 16 + c) * 64 +
                             (((kk * 4 + quad) ^ (c & 7)) << 3)];
                oacc[nt] = __builtin_amdgcn_mfma_f32_16x16x32_bf16(
                    pf[kk], vf, oacc[nt], 0, 0, 0);
            }
    };

    auto write_out = [&]() {
        float l = lsum;
        l += __shfl_xor(l, 16);
        l += __shfl_xor(l, 32);
        float il = 1.f / l;
        float ilr[4];
#pragma unroll
        for (int reg = 0; reg < 4; ++reg)
            ilr[reg] = __shfl(il, quad * 4 + reg);
#pragma unroll
        for (int reg = 0; reg < 4; ++reg) {
            int t_o = q0 + gw * 16 + quad * 4 + reg;
#pragma unroll
            for (int nt = 0; nt < 4; ++nt)
                att[(size_t)(b * Tc + t_o) * Cc + h * Dc + nt * 16 + c] =
                    f2bf(oacc[nt][reg] * ilr[reg]);
        }
    };

    // ---- phase 1: jt = 0..p, shared staging, prefetch jt+1 (v6 verbatim)
    stageK_all(0, 0); stageV_all(0, 0);
    for (int jt = 0; jt <= p; ++jt) {
        __syncthreads();
        stageK_all(jt + 1, (jt + 1) & 1);      // jt==p stages B's first ph2 tile
        stageV_all(jt + 1, (jt + 1) & 1);
        do_s(jt, jt & 1);
        do_pv(jt & 1);
    }
    const int slotB = (p + 1) & 1, slotA = slotB ^ 1;

    // ---- transition
    __syncthreads();                           // tile p+1 landed; phase-1 reads done
    if (tx == 0) {
        write_out();                           // qA complete
#pragma unroll
        for (int nt = 0; nt < 4; ++nt)
            oacc[nt] = (f32x4){0.f, 0.f, 0.f, 0.f};
        lsum = 0.f;
        qcur = qB; q0 = qB * 64;
        const short* qp = q2b + (size_t)(q0 + t_l) * 128;
#pragma unroll
        for (int i = 0; i < 4; ++i)
            qf[i] = *(const short8*)(qp + i * 32 + quad * 8);
        float a = th * 0.125f * (1088.f - (float)(q0 + t_l));   // base @ jt=17
        __sincosf(a, &sb, &cb);
    } else {
        do_s(p + 1, slotB);                    // diag here only when p==15
        do_pv(slotB);
    }

    // ---- phase 2: 15-p iterations, both groups busy, own slot, no dbuf
    for (int i = 0; i <= 14 - p; ++i) {
        const int jt = tx ? (p + 2 + i) : (17 + i);
        const int sl = tx ? slotB : slotA;
        __syncthreads();                       // WAR: previous reads done
        stage_grp(jt, sl);
        __syncthreads();                       // RAW: loads landed (vmcnt drain)
        do_s(jt, sl);
        do_pv(sl);
    }

    // ---- combine qB partials: A -> LDS (reuse Ks), B adds + writes
    __syncthreads();
    float* Cmb = (float*)&Ks[0][0];            // 256 x 20 f32 = 20 KB of 32 KB
    if (tx == 0) {
        float* pp = Cmb + (size_t)(gw * 64 + lane) * 20;
#pragma unroll
        for (int nt = 0; nt < 4; ++nt) *(f32x4*)(pp + nt * 4) = oacc[nt];
        pp[16] = lsum;
    }
    __syncthreads();
    if (tx == 1) {
        const float* pp = Cmb + (size_t)(gw * 64 + lane) * 20;
#pragma unroll
        for (int nt = 0; nt < 4; ++nt)
            oacc[nt] += *(const f32x4*)(pp + nt * 4);
        lsum += pp[16];
        write_out();
    }
}

// ---------------------------------------------------------------------------
extern "C" void kernel_launch(void* const* d_in, const int* in_sizes, int n_in,
                              void* d_out, int out_size, void* d_ws, size_t ws_size,
                              hipStream_t stream)
{
    const float* x     = (const float*)d_in[0];
    const float* Wq    = (const float*)d_in[1];
    const float* Wk    = (const float*)d_in[2];
    const float* Wv    = (const float*)d_in[3];
    const float* Wo    = (const float*)d_in[4];
    const float* theta = (const float*)d_in[5];
    float* out = (float*)d_out;

    const int M = Bc * Tc;                 // 4096
    char* ws = (char*)d_ws;
    const size_t MB = 1 << 20;
    short* xb   = (short*)(ws);             // [0,8)   x bf16
    short* Bqk  = (short*)(ws + 8 * MB);    // [8,16)  permuted [Wq'|Wk']^T bf16
    short* Wvt  = (short*)(ws + 16 * MB);   // [16,18)
    short* Wot  = (short*)(ws + 18 * MB);   // [18,20)
    short* v2t  = (short*)(ws + 28 * MB);   // [28,36) bf16 (B,H,D,T)
    short* attb = (short*)(ws + 36 * MB);   // [36,44)
    short* q2   = (short*)(ws + 44 * MB);   // [44,60) bf16 (B,H,T,128)
    short* k2   = (short*)d_out;            // 16 MB   bf16 (B,H,T,128) until final gemm

    xconv<<<(size_t)M * Cc / 1024, 256, 0, stream>>>(x, xb);
    wtrans_qk<<<dim3(2048 / 64, Cc / 64, 2), 256, 0, stream>>>(Wq, Wk, Bqk);
    wtrans2<<<dim3(Cc / 64, Cc / 64, 2), 256, 0, stream>>>(Wv, Wo, Wvt);

    // fused QK projection + moire transform (256^2 8-phase, writes q2, k2)
    gemm256_qk<<<dim3(4096 / 256, M / 256), 512, 0, stream>>>(xb, Bqk, q2, k2);
    // fused V projection + head-transpose (128x64 tiles -> 512 blocks, 2/CU)
    gemm_v2t64<<<dim3(Cc / 64, M / 128), 256, 0, stream>>>(xb, Wvt, v2t);

    moire_attn8<<<dim3(16, Hc, Bc), 512, 0, stream>>>(q2, k2, v2t, theta, attb);

    // Wo projection (128x64 tiles -> 512 blocks, 2/CU)
    gemm_bt64<<<dim3(Cc / 64, M / 128), 256, 0, stream>>>(
        attb, Wot, out, M, Cc, Cc);
}